// Round 1
// baseline (274.906 us; speedup 1.0000x reference)
//
#include <hip/hip_runtime.h>
#include <cstdint>
#include <cstddef>

// Problem constants
#define BB 8
#define TT 1024
#define CC 768
#define NH 12
#define HD 64
// N of QKV gemm = 2304, K = 768

using bf16x8 = __attribute__((ext_vector_type(8))) short;  // 8 bf16 (4 VGPRs)
using f32x4  = __attribute__((ext_vector_type(4))) float;  // 4 fp32

static __device__ __forceinline__ short f2bf(float f) {
    uint32_t u;
    __builtin_memcpy(&u, &f, 4);
    u += 0x7FFFu + ((u >> 16) & 1u);   // RNE
    return (short)(u >> 16);
}

// ---------------------------------------------------------------- fc table
__global__ void fc_kernel(float2* __restrict__ fc) {
    int idx = blockIdx.x * 256 + threadIdx.x;   // 32768 = 1024*32
    int t = idx >> 5, p = idx & 31;
    float freq = powf(10000.0f, -(float)p / 32.0f);
    float a = (float)t * freq;
    fc[idx] = make_float2(cosf(a), sinf(a));
}

// ------------------------------------------- transpose fp32 [R][C] -> bf16 [C][R]
__global__ __launch_bounds__(256)
void transpose_cast_kernel(const float* __restrict__ in, short* __restrict__ out,
                           int R, int Cdim) {
    __shared__ float tile[32][33];
    int tx = threadIdx.x, ty = threadIdx.y;
    int c0 = blockIdx.x * 32, r0 = blockIdx.y * 32;
#pragma unroll
    for (int i = 0; i < 4; i++)
        tile[ty + 8 * i][tx] = in[(size_t)(r0 + ty + 8 * i) * Cdim + c0 + tx];
    __syncthreads();
#pragma unroll
    for (int i = 0; i < 4; i++)
        out[(size_t)(c0 + ty + 8 * i) * R + r0 + tx] = f2bf(tile[tx][ty + 8 * i]);
}

// ---------------------------------------------------------------- GEMM
// C[M,N] = A[M,K] @ B[K,N] + bias, with B given pre-transposed bf16 BT[N][K].
// 128x128 tile, 4 waves (2x2), each wave 64x64 = 4x4 frags of 16x16, BK=64.
// EPI 0: qkv epilogue (RoPE + scatter to Q/K/V bf16 [B][H][T][HD], Q pre-scaled 0.125)
// EPI 1: proj epilogue (fp32 out)
template <bool AF32, int EPI>
__global__ __launch_bounds__(256)
void gemm_kernel(const void* __restrict__ Av, const short* __restrict__ BT,
                 const float* __restrict__ bias, int Kdim,
                 short* __restrict__ Qb, short* __restrict__ Kb, short* __restrict__ Vb,
                 const float2* __restrict__ fc, float* __restrict__ out) {
    __shared__ short As[128 * 64];
    __shared__ short Bs[128 * 64];
    const int tid = threadIdx.x;
    const int lane = tid & 63, wid = tid >> 6;
    const int g = lane >> 4, c = lane & 15;
    const int wm = wid >> 1, wn = wid & 1;
    const int m0 = blockIdx.y * 128, n0 = blockIdx.x * 128;

    const f32x4 zero4 = {0.f, 0.f, 0.f, 0.f};
    f32x4 acc[4][4];
#pragma unroll
    for (int i = 0; i < 4; i++)
#pragma unroll
        for (int j = 0; j < 4; j++) acc[i][j] = zero4;

    const int row_s = tid >> 3;  // 0..31
    const int kg = tid & 7;

    for (int k0 = 0; k0 < Kdim; k0 += 64) {
        // stage A (fp32 -> bf16 or straight bf16 copy), XOR-swizzled
        if (AF32) {
            const float* Ap = (const float*)Av;
#pragma unroll
            for (int i = 0; i < 4; i++) {
                int row = row_s + 32 * i;
                const float* src = Ap + (size_t)(m0 + row) * Kdim + k0 + kg * 8;
                float4 f0 = *(const float4*)src;
                float4 f1 = *(const float4*)(src + 4);
                bf16x8 hv;
                hv[0] = f2bf(f0.x); hv[1] = f2bf(f0.y); hv[2] = f2bf(f0.z); hv[3] = f2bf(f0.w);
                hv[4] = f2bf(f1.x); hv[5] = f2bf(f1.y); hv[6] = f2bf(f1.z); hv[7] = f2bf(f1.w);
                *(bf16x8*)(&As[row * 64 + ((kg ^ (row & 7)) * 8)]) = hv;
            }
        } else {
            const short* Ap = (const short*)Av;
#pragma unroll
            for (int i = 0; i < 4; i++) {
                int row = row_s + 32 * i;
                bf16x8 hv = *(const bf16x8*)(Ap + (size_t)(m0 + row) * Kdim + k0 + kg * 8);
                *(bf16x8*)(&As[row * 64 + ((kg ^ (row & 7)) * 8)]) = hv;
            }
        }
        // stage B from BT [N][K] bf16
#pragma unroll
        for (int i = 0; i < 4; i++) {
            int row = row_s + 32 * i;
            bf16x8 hv = *(const bf16x8*)(BT + (size_t)(n0 + row) * Kdim + k0 + kg * 8);
            *(bf16x8*)(&Bs[row * 64 + ((kg ^ (row & 7)) * 8)]) = hv;
        }
        __syncthreads();
#pragma unroll
        for (int kk = 0; kk < 2; kk++) {
            bf16x8 af[4], bfr[4];
#pragma unroll
            for (int mi = 0; mi < 4; mi++) {
                int row = wm * 64 + mi * 16 + c;
                af[mi] = *(const bf16x8*)(&As[row * 64 + (((kk * 4 + g) ^ (c & 7)) * 8)]);
            }
#pragma unroll
            for (int ni = 0; ni < 4; ni++) {
                int row = wn * 64 + ni * 16 + c;
                bfr[ni] = *(const bf16x8*)(&Bs[row * 64 + (((kk * 4 + g) ^ (c & 7)) * 8)]);
            }
#pragma unroll
            for (int mi = 0; mi < 4; mi++)
#pragma unroll
                for (int ni = 0; ni < 4; ni++)
                    acc[mi][ni] = __builtin_amdgcn_mfma_f32_16x16x32_bf16(
                        af[mi], bfr[ni], acc[mi][ni], 0, 0, 0);
        }
        __syncthreads();
    }

    // epilogue. C frag: col = n-tile + c, row = m-tile + 4g + r
#pragma unroll
    for (int mi = 0; mi < 4; mi++) {
#pragma unroll
        for (int ni = 0; ni < 4; ni++) {
            int n = n0 + wn * 64 + ni * 16 + c;
            float bv = bias[n];
#pragma unroll
            for (int r = 0; r < 4; r++) {
                int m = m0 + wm * 64 + mi * 16 + g * 4 + r;
                float v = acc[mi][ni][r] + bv;
                if (EPI == 0) {
                    float pv = __shfl_xor(v, 1);  // partner col n^1 (all lanes)
                    int part = (n >= 1536) ? 2 : (n >= 768 ? 1 : 0);
                    int rem = n - part * 768;
                    int h = rem >> 6, d = rem & 63;
                    int b = m >> 10, t = m & 1023;
                    if (part < 2) {
                        float2 cs = fc[t * 32 + (d >> 1)];
                        v = (d & 1) ? (pv * cs.y + v * cs.x) : (v * cs.x - pv * cs.y);
                        if (part == 0) v *= 0.125f;  // fold 1/sqrt(HD), exact in bf16
                    }
                    size_t idx = (((size_t)b * NH + h) * TT + t) * HD + d;
                    (part == 0 ? Qb : part == 1 ? Kb : Vb)[idx] = f2bf(v);
                } else {
                    out[(size_t)m * CC + n] = v;
                }
            }
        }
    }
}

// ---------------------------------------------------------------- flash attention
// grid (16 qtiles, 96 bh). 4 waves x 16 q-rows, KV tile 64, causal.
__global__ __launch_bounds__(256)
void attn_kernel(const short* __restrict__ Qb, const short* __restrict__ Kb,
                 const short* __restrict__ Vb, short* __restrict__ Ob) {
    __shared__ short Vt[64 * 64];       // V^T tile, swizzled
    __shared__ short Pl[4][16 * 64];    // per-wave P tile, swizzled
    const int tid = threadIdx.x;
    const int lane = tid & 63, wid = tid >> 6;
    const int g = lane >> 4, c = lane & 15;
    const int qt = blockIdx.x, bh = blockIdx.y;
    const int b = bh / NH, h = bh % NH;
    const int qbase = qt * 64;
    const short* Qp = Qb + (size_t)bh * TT * HD;
    const short* Kp = Kb + (size_t)bh * TT * HD;
    const short* Vp = Vb + (size_t)bh * TT * HD;

    // Q A-fragments (held in regs whole kernel); Q was pre-scaled by 0.125
    const int qr = qbase + wid * 16 + c;
    bf16x8 aq0 = *(const bf16x8*)(Qp + (size_t)qr * HD + g * 8);
    bf16x8 aq1 = *(const bf16x8*)(Qp + (size_t)qr * HD + 32 + g * 8);

    const f32x4 zero4 = {0.f, 0.f, 0.f, 0.f};
    f32x4 onT[4];
#pragma unroll
    for (int i = 0; i < 4; i++) onT[i] = zero4;
    float mrun[4], lrun[4];
#pragma unroll
    for (int r = 0; r < 4; r++) { mrun[r] = -__builtin_inff(); lrun[r] = 0.f; }

    const int kvs = tid >> 3;  // 0..31
    const int dg = tid & 7;

    for (int t0 = 0; t0 <= qbase; t0 += 64) {
        __syncthreads();  // prev iter done reading Vt
        // stage V^T (swizzled): Vt[d][kv]
#pragma unroll
        for (int i = 0; i < 2; i++) {
            int kv = kvs + 32 * i;
            bf16x8 vv = *(const bf16x8*)(Vp + (size_t)(t0 + kv) * HD + dg * 8);
#pragma unroll
            for (int j = 0; j < 8; j++) {
                int d = dg * 8 + j;
                Vt[d * 64 + (kv ^ ((d & 7) * 8))] = vv[j];
            }
        }
        __syncthreads();

        // S = Q K^T  (4 kv sub-tiles of 16)
        f32x4 s[4];
#pragma unroll
        for (int nt = 0; nt < 4; nt++) {
            const short* kp = Kp + (size_t)(t0 + nt * 16 + c) * HD + g * 8;
            bf16x8 k0v = *(const bf16x8*)kp;
            bf16x8 k1v = *(const bf16x8*)(kp + 32);
            f32x4 z = zero4;
            z = __builtin_amdgcn_mfma_f32_16x16x32_bf16(aq0, k0v, z, 0, 0, 0);
            z = __builtin_amdgcn_mfma_f32_16x16x32_bf16(aq1, k1v, z, 0, 0, 0);
            s[nt] = z;
        }
        // causal mask
#pragma unroll
        for (int nt = 0; nt < 4; nt++)
#pragma unroll
            for (int r = 0; r < 4; r++) {
                int kvg = t0 + nt * 16 + c;
                int qg = qbase + wid * 16 + g * 4 + r;
                if (kvg > qg) s[nt][r] = -1e30f;
            }
        // online softmax (wave-parallel row reduce over 16 lanes)
        float mnew[4], alpha[4];
#pragma unroll
        for (int r = 0; r < 4; r++) {
            float mx = fmaxf(fmaxf(s[0][r], s[1][r]), fmaxf(s[2][r], s[3][r]));
            mx = fmaxf(mx, __shfl_xor(mx, 1));
            mx = fmaxf(mx, __shfl_xor(mx, 2));
            mx = fmaxf(mx, __shfl_xor(mx, 4));
            mx = fmaxf(mx, __shfl_xor(mx, 8));
            mnew[r] = fmaxf(mrun[r], mx);
            alpha[r] = __expf(mrun[r] - mnew[r]);
            mrun[r] = mnew[r];
        }
#pragma unroll
        for (int nt = 0; nt < 4; nt++)
#pragma unroll
            for (int r = 0; r < 4; r++) s[nt][r] = __expf(s[nt][r] - mnew[r]);
#pragma unroll
        for (int r = 0; r < 4; r++) {
            float sm = s[0][r] + s[1][r] + s[2][r] + s[3][r];
            sm += __shfl_xor(sm, 1);
            sm += __shfl_xor(sm, 2);
            sm += __shfl_xor(sm, 4);
            sm += __shfl_xor(sm, 8);
            lrun[r] = lrun[r] * alpha[r] + sm;
            onT[0][r] *= alpha[r]; onT[1][r] *= alpha[r];
            onT[2][r] *= alpha[r]; onT[3][r] *= alpha[r];
        }
        // P -> per-wave LDS (swizzled), then PV
        short* pw = &Pl[wid][0];
#pragma unroll
        for (int nt = 0; nt < 4; nt++)
#pragma unroll
            for (int r = 0; r < 4; r++) {
                int q = g * 4 + r, kv = nt * 16 + c;
                pw[q * 64 + (kv ^ ((q & 7) * 8))] = f2bf(s[nt][r]);
            }
#pragma unroll
        for (int H = 0; H < 2; H++) {
            bf16x8 pa = *(const bf16x8*)(&pw[c * 64 + (((H * 4 + g) ^ (c & 7)) * 8)]);
#pragma unroll
            for (int nt = 0; nt < 4; nt++) {
                bf16x8 vb = *(const bf16x8*)(&Vt[(nt * 16 + c) * 64 + (((H * 4 + g) ^ (c & 7)) * 8)]);
                onT[nt] = __builtin_amdgcn_mfma_f32_16x16x32_bf16(pa, vb, onT[nt], 0, 0, 0);
            }
        }
    }
    // normalize + write O as bf16 [B*T][C] (GEMM2 A layout)
#pragma unroll
    for (int r = 0; r < 4; r++) {
        float inv = 1.0f / lrun[r];
        int t = qbase + wid * 16 + g * 4 + r;
        size_t rowo = ((size_t)b * TT + t) * CC + h * HD;
#pragma unroll
        for (int nt = 0; nt < 4; nt++)
            Ob[rowo + nt * 16 + c] = f2bf(onT[nt][r] * inv);
    }
}

// ---------------------------------------------------------------- launch
extern "C" void kernel_launch(void* const* d_in, const int* in_sizes, int n_in,
                              void* d_out, int out_size, void* d_ws, size_t ws_size,
                              hipStream_t stream) {
    const float* x    = (const float*)d_in[0];
    const float* Wqkv = (const float*)d_in[1];
    const float* bqkv = (const float*)d_in[2];
    const float* Wproj = (const float*)d_in[3];
    const float* bproj = (const float*)d_in[4];
    // d_in[5] = mask: causal by construction, unused

    char* ws = (char*)d_ws;
    // ws layout (bytes): WqkvT 3538944 | WprojT 1179648 | fc 262144 | Q,K,V,O 12582912 each
    short*  WqkvT  = (short*)(ws);
    short*  WprojT = (short*)(ws + 3538944);
    float2* fc     = (float2*)(ws + 3538944 + 1179648);
    short*  Qb     = (short*)(ws + 4980736);
    short*  Kb     = (short*)(ws + 4980736 + 1 * 12582912);
    short*  Vb     = (short*)(ws + 4980736 + 2 * 12582912);
    short*  Ob     = (short*)(ws + 4980736 + 3 * 12582912);
    float*  out    = (float*)d_out;

    hipLaunchKernelGGL(fc_kernel, dim3(128), dim3(256), 0, stream, fc);
    hipLaunchKernelGGL(transpose_cast_kernel, dim3(72, 24), dim3(32, 8), 0, stream,
                       Wqkv, WqkvT, 768, 2304);
    hipLaunchKernelGGL(transpose_cast_kernel, dim3(24, 24), dim3(32, 8), 0, stream,
                       Wproj, WprojT, 768, 768);
    hipLaunchKernelGGL((gemm_kernel<true, 0>), dim3(18, 64), dim3(256), 0, stream,
                       (const void*)x, WqkvT, bqkv, 768, Qb, Kb, Vb, fc, (float*)nullptr);
    hipLaunchKernelGGL(attn_kernel, dim3(16, 96), dim3(256), 0, stream, Qb, Kb, Vb, Ob);
    hipLaunchKernelGGL((gemm_kernel<false, 1>), dim3(6, 64), dim3(256), 0, stream,
                       (const void*)Ob, WprojT, bproj, 768,
                       (short*)nullptr, (short*)nullptr, (short*)nullptr,
                       (const float2*)nullptr, out);
}

// Round 3
// 195.242 us; speedup vs baseline: 1.4080x; 1.4080x over previous
//
#include <hip/hip_runtime.h>
#include <cstdint>
#include <cstddef>

// Problem constants
#define BB 8
#define TT 1024
#define CC 768
#define NH 12
#define HD 64
// N of QKV gemm = 2304, K = 768

using bf16x8 = __attribute__((ext_vector_type(8))) short;  // 8 bf16 (4 VGPRs)
using f32x4  = __attribute__((ext_vector_type(4))) float;  // 4 fp32

static __device__ __forceinline__ short f2bf(float f) {
    uint32_t u;
    __builtin_memcpy(&u, &f, 4);
    u += 0x7FFFu + ((u >> 16) & 1u);   // RNE
    return (short)(u >> 16);
}

static __device__ __forceinline__ uint32_t bfpack(float lo, float hi) {
    return (uint32_t)(uint16_t)f2bf(lo) | ((uint32_t)(uint16_t)f2bf(hi) << 16);
}

// ---------------------------------------------------------------- fc table
__global__ void fc_kernel(float2* __restrict__ fc) {
    int idx = blockIdx.x * 256 + threadIdx.x;   // 32768 = 1024*32
    int t = idx >> 5, p = idx & 31;
    float freq = powf(10000.0f, -(float)p / 32.0f);
    float a = (float)t * freq;
    fc[idx] = make_float2(cosf(a), sinf(a));
}

// ------------------------------------------- transpose fp32 [R][C] -> bf16 [C][R]
__global__ __launch_bounds__(256)
void transpose_cast_kernel(const float* __restrict__ in, short* __restrict__ out,
                           int R, int Cdim) {
    __shared__ float tile[32][33];
    int tx = threadIdx.x, ty = threadIdx.y;
    int c0 = blockIdx.x * 32, r0 = blockIdx.y * 32;
#pragma unroll
    for (int i = 0; i < 4; i++)
        tile[ty + 8 * i][tx] = in[(size_t)(r0 + ty + 8 * i) * Cdim + c0 + tx];
    __syncthreads();
#pragma unroll
    for (int i = 0; i < 4; i++)
        out[(size_t)(c0 + ty + 8 * i) * R + r0 + tx] = f2bf(tile[tx][ty + 8 * i]);
}

// ------------------------------------------- V [bh][t][64] -> VT [bh][64][t] (bf16)
__global__ __launch_bounds__(256)
void vtrans_kernel(const short* __restrict__ V, short* __restrict__ VT) {
    __shared__ short tl[64][72];
    const int tid = threadIdx.x;
    const int bh = blockIdx.y, t0 = blockIdx.x * 64;
    {
        int r = tid >> 2, cs = (tid & 3) * 16;
        const short* src = V + (size_t)bh * TT * HD + (size_t)(t0 + r) * HD + cs;
        *(bf16x8*)&tl[r][cs]     = *(const bf16x8*)src;
        *(bf16x8*)&tl[r][cs + 8] = *(const bf16x8*)(src + 8);
    }
    __syncthreads();
    {
        int d = tid >> 2, ts = (tid & 3) * 16;
        bf16x8 o0, o1;
#pragma unroll
        for (int e = 0; e < 8; e++) { o0[e] = tl[ts + e][d]; o1[e] = tl[ts + 8 + e][d]; }
        short* dst = VT + (size_t)bh * TT * HD + (size_t)d * TT + t0 + ts;
        *(bf16x8*)dst       = o0;
        *(bf16x8*)(dst + 8) = o1;
    }
}

// ---------------------------------------------------------------- GEMM
// C[M,N] = A[M,K] @ B[K,N] + bias, with B given pre-transposed bf16 BT[N][K].
// 128x128 tile, 4 waves (2x2), each wave 64x64 = 4x4 frags of 16x16, BK=64.
// EPI 0: qkv epilogue (RoPE + scatter to Q/K/V bf16 [B][H][T][HD], Q pre-scaled 0.125)
// EPI 1: proj epilogue (fp32 out)
template <bool AF32, int EPI>
__global__ __launch_bounds__(256)
void gemm_kernel(const void* __restrict__ Av, const short* __restrict__ BT,
                 const float* __restrict__ bias, int Kdim,
                 short* __restrict__ Qb, short* __restrict__ Kb, short* __restrict__ Vb,
                 const float2* __restrict__ fc, float* __restrict__ out) {
    __shared__ short As[128 * 64];
    __shared__ short Bs[128 * 64];
    const int tid = threadIdx.x;
    const int lane = tid & 63, wid = tid >> 6;
    const int g = lane >> 4, c = lane & 15;
    const int wm = wid >> 1, wn = wid & 1;
    const int m0 = blockIdx.y * 128, n0 = blockIdx.x * 128;

    const f32x4 zero4 = {0.f, 0.f, 0.f, 0.f};
    f32x4 acc[4][4];
#pragma unroll
    for (int i = 0; i < 4; i++)
#pragma unroll
        for (int j = 0; j < 4; j++) acc[i][j] = zero4;

    const int row_s = tid >> 3;  // 0..31
    const int kg = tid & 7;

    for (int k0 = 0; k0 < Kdim; k0 += 64) {
        if (AF32) {
            const float* Ap = (const float*)Av;
#pragma unroll
            for (int i = 0; i < 4; i++) {
                int row = row_s + 32 * i;
                const float* src = Ap + (size_t)(m0 + row) * Kdim + k0 + kg * 8;
                float4 f0 = *(const float4*)src;
                float4 f1 = *(const float4*)(src + 4);
                bf16x8 hv;
                hv[0] = f2bf(f0.x); hv[1] = f2bf(f0.y); hv[2] = f2bf(f0.z); hv[3] = f2bf(f0.w);
                hv[4] = f2bf(f1.x); hv[5] = f2bf(f1.y); hv[6] = f2bf(f1.z); hv[7] = f2bf(f1.w);
                *(bf16x8*)(&As[row * 64 + ((kg ^ (row & 7)) * 8)]) = hv;
            }
        } else {
            const short* Ap = (const short*)Av;
#pragma unroll
            for (int i = 0; i < 4; i++) {
                int row = row_s + 32 * i;
                bf16x8 hv = *(const bf16x8*)(Ap + (size_t)(m0 + row) * Kdim + k0 + kg * 8);
                *(bf16x8*)(&As[row * 64 + ((kg ^ (row & 7)) * 8)]) = hv;
            }
        }
#pragma unroll
        for (int i = 0; i < 4; i++) {
            int row = row_s + 32 * i;
            bf16x8 hv = *(const bf16x8*)(BT + (size_t)(n0 + row) * Kdim + k0 + kg * 8);
            *(bf16x8*)(&Bs[row * 64 + ((kg ^ (row & 7)) * 8)]) = hv;
        }
        __syncthreads();
#pragma unroll
        for (int kk = 0; kk < 2; kk++) {
            bf16x8 af[4], bfr[4];
#pragma unroll
            for (int mi = 0; mi < 4; mi++) {
                int row = wm * 64 + mi * 16 + c;
                af[mi] = *(const bf16x8*)(&As[row * 64 + (((kk * 4 + g) ^ (c & 7)) * 8)]);
            }
#pragma unroll
            for (int ni = 0; ni < 4; ni++) {
                int row = wn * 64 + ni * 16 + c;
                bfr[ni] = *(const bf16x8*)(&Bs[row * 64 + (((kk * 4 + g) ^ (c & 7)) * 8)]);
            }
#pragma unroll
            for (int mi = 0; mi < 4; mi++)
#pragma unroll
                for (int ni = 0; ni < 4; ni++)
                    acc[mi][ni] = __builtin_amdgcn_mfma_f32_16x16x32_bf16(
                        af[mi], bfr[ni], acc[mi][ni], 0, 0, 0);
        }
        __syncthreads();
    }

#pragma unroll
    for (int mi = 0; mi < 4; mi++) {
#pragma unroll
        for (int ni = 0; ni < 4; ni++) {
            int n = n0 + wn * 64 + ni * 16 + c;
            float bv = bias[n];
#pragma unroll
            for (int r = 0; r < 4; r++) {
                int m = m0 + wm * 64 + mi * 16 + g * 4 + r;
                float v = acc[mi][ni][r] + bv;
                if (EPI == 0) {
                    float pv = __shfl_xor(v, 1);  // partner col n^1 (all lanes)
                    int part = (n >= 1536) ? 2 : (n >= 768 ? 1 : 0);
                    int rem = n - part * 768;
                    int h = rem >> 6, d = rem & 63;
                    int b = m >> 10, t = m & 1023;
                    if (part < 2) {
                        float2 cs = fc[t * 32 + (d >> 1)];
                        v = (d & 1) ? (pv * cs.y + v * cs.x) : (v * cs.x - pv * cs.y);
                        if (part == 0) v *= 0.125f;  // fold 1/sqrt(HD), exact in bf16
                    }
                    size_t idx = (((size_t)b * NH + h) * TT + t) * HD + d;
                    (part == 0 ? Qb : part == 1 ? Kb : Vb)[idx] = f2bf(v);
                } else {
                    out[(size_t)m * CC + n] = v;
                }
            }
        }
    }
}

// ---------------------------------------------------------------- flash attention
// Swapped-operand structure: S^T = mfma(K, Q) so q is lane-fixed (col=lane&15).
// Softmax is lane-local + 2 shfl. S^T C-frag (kv=4g+r per 16-subtile) goes through
// a per-wave swizzled LDS P-tile (no barriers; same-wave LDS ops are in-order) and
// comes back as the x32 PV B-frag (kv=8g..8g+7). Only the session-verified
// mfma_f32_16x16x32_bf16 is used. V consumed directly from global VT[bh][d][t]
// (L2-resident). Block = 4 waves x 32 q-rows = 128 q. Grid (96 bh, 8 qb),
// heavy-first qb = 7 - by. Epilogue transposes O^T via swizzled LDS.
__global__ __launch_bounds__(256)
void attn_kernel(const short* __restrict__ Qb, const short* __restrict__ Kb,
                 const short* __restrict__ VT, short* __restrict__ Ob) {
    __shared__ uint32_t Pt[4][32][32];  // 16 KB: per-wave P tile [q-row][kv-word], XOR-swizzled
    __shared__ uint32_t ot[128 * 32];   // 16 KB: epilogue O^T transpose
    const int tid = threadIdx.x, lane = tid & 63, wid = tid >> 6;
    const int g = lane >> 4, c = lane & 15;
    const int bh = blockIdx.x, qb = 7 - (int)blockIdx.y;
    const int b = bh / NH, h = bh % NH;
    const short* Qp = Qb + (size_t)bh * TT * HD;
    const short* Kp = Kb + (size_t)bh * TT * HD;
    const short* Vp = VT + (size_t)bh * TT * HD;
    const int q0 = qb * 128 + wid * 32;
    const int sw = (c & 7) << 2;        // word-index swizzle (row&7 == c&7)

    // Q B-frags (col=q), held whole kernel; Q pre-scaled 0.125 in GEMM1
    bf16x8 qf[2][2];
#pragma unroll
    for (int qs = 0; qs < 2; qs++)
#pragma unroll
        for (int kh = 0; kh < 2; kh++)
            qf[qs][kh] = *(const bf16x8*)(Qp + (size_t)(q0 + qs * 16 + c) * HD + kh * 32 + g * 8);

    const f32x4 zero4 = {0.f, 0.f, 0.f, 0.f};
    f32x4 o[2][4];   // O^T[d=dt*16+4g+r][q=c] per qs
#pragma unroll
    for (int qs = 0; qs < 2; qs++)
#pragma unroll
        for (int dt = 0; dt < 4; dt++) o[qs][dt] = zero4;
    float mrun[2] = {-1e30f, -1e30f}, lrun[2] = {0.f, 0.f};

    const int t0max = ((q0 + 31) >> 6) << 6;
    for (int t0 = 0; t0 <= t0max; t0 += 64) {
        // S^T = K x Q^T  (row kv, col q)
        f32x4 st[2][4];
#pragma unroll
        for (int nt = 0; nt < 4; nt++) {
            const short* kp = Kp + (size_t)(t0 + nt * 16 + c) * HD + g * 8;
            bf16x8 k0 = *(const bf16x8*)kp;
            bf16x8 k1 = *(const bf16x8*)(kp + 32);
#pragma unroll
            for (int qs = 0; qs < 2; qs++) {
                f32x4 z = zero4;
                z = __builtin_amdgcn_mfma_f32_16x16x32_bf16(k0, qf[qs][0], z, 0, 0, 0);
                z = __builtin_amdgcn_mfma_f32_16x16x32_bf16(k1, qf[qs][1], z, 0, 0, 0);
                st[qs][nt] = z;
            }
        }
        // V A-frags for PV (issued early; softmax VALU hides the latency)
        bf16x8 vf[2][4];
#pragma unroll
        for (int blk = 0; blk < 2; blk++)
#pragma unroll
            for (int dt = 0; dt < 4; dt++)
                vf[blk][dt] = *(const bf16x8*)(Vp + (size_t)(dt * 16 + c) * TT + t0 + blk * 32 + g * 8);
        // causal mask (wave-uniform branch; at most 1-2 trips)
        if (t0 + 63 > q0) {
#pragma unroll
            for (int qs = 0; qs < 2; qs++) {
                int q = q0 + qs * 16 + c;
#pragma unroll
                for (int nt = 0; nt < 4; nt++)
#pragma unroll
                    for (int r = 0; r < 4; r++)
                        if (t0 + nt * 16 + g * 4 + r > q) st[qs][nt][r] = -1e30f;
            }
        }
        // online softmax (lane-local: this lane owns column q) + P -> per-wave LDS
#pragma unroll
        for (int qs = 0; qs < 2; qs++) {
            float mx = st[qs][0][0];
#pragma unroll
            for (int nt = 0; nt < 4; nt++)
#pragma unroll
                for (int r = 0; r < 4; r++) mx = fmaxf(mx, st[qs][nt][r]);
            mx = fmaxf(mx, __shfl_xor(mx, 16));
            mx = fmaxf(mx, __shfl_xor(mx, 32));
            float mnew = fmaxf(mrun[qs], mx);
            float al = __expf(mrun[qs] - mnew);
            mrun[qs] = mnew;
            float sm = 0.f;
#pragma unroll
            for (int nt = 0; nt < 4; nt++)
#pragma unroll
                for (int r = 0; r < 4; r++) {
                    float e = __expf(st[qs][nt][r] - mnew);
                    st[qs][nt][r] = e;
                    sm += e;
                }
            sm += __shfl_xor(sm, 16);
            sm += __shfl_xor(sm, 32);
            lrun[qs] = lrun[qs] * al + sm;
#pragma unroll
            for (int dt = 0; dt < 4; dt++) {
                o[qs][dt][0] *= al; o[qs][dt][1] *= al;
                o[qs][dt][2] *= al; o[qs][dt][3] *= al;
            }
            int row = qs * 16 + c;
#pragma unroll
            for (int nt = 0; nt < 4; nt++) {
                uint32_t w0 = bfpack(st[qs][nt][0], st[qs][nt][1]);  // kv = nt*16+4g, +1
                uint32_t w1 = bfpack(st[qs][nt][2], st[qs][nt][3]);  // kv = nt*16+4g+2, +3
                int wa = nt * 8 + 2 * g;
                Pt[wid][row][wa ^ sw]       = w0;
                Pt[wid][row][(wa + 1) ^ sw] = w1;
            }
        }
        // PV: O^T += V^T-frag x P-frag (x32 MFMA; P B-frag re-read from LDS)
#pragma unroll
        for (int qs = 0; qs < 2; qs++) {
            int row = qs * 16 + c;
#pragma unroll
            for (int blk = 0; blk < 2; blk++) {
                bf16x8 pf = *(const bf16x8*)&Pt[wid][row][(blk * 16 + 4 * g) ^ sw];
#pragma unroll
                for (int dt = 0; dt < 4; dt++)
                    o[qs][dt] = __builtin_amdgcn_mfma_f32_16x16x32_bf16(
                        vf[blk][dt], pf, o[qs][dt], 0, 0, 0);
            }
        }
    }

    // epilogue: O^T -> LDS (swizzled) -> coalesced bf16 rows of Ob [B*T][C]
#pragma unroll
    for (int qs = 0; qs < 2; qs++) {
        float inv = 1.0f / lrun[qs];
        int ql = wid * 32 + qs * 16 + c;
#pragma unroll
        for (int dt = 0; dt < 4; dt++) {
            uint32_t w0 = bfpack(o[qs][dt][0] * inv, o[qs][dt][1] * inv);
            uint32_t w1 = bfpack(o[qs][dt][2] * inv, o[qs][dt][3] * inv);
            int jc0 = dt * 8 + 2 * g;
            int jc1 = jc0 + 1;
            ot[ql * 32 + ((((jc0 >> 2) ^ (c & 7)) << 2) | (jc0 & 3))] = w0;
            ot[ql * 32 + ((((jc1 >> 2) ^ (c & 7)) << 2) | (jc1 & 3))] = w1;
        }
    }
    __syncthreads();
#pragma unroll
    for (int p = 0; p < 4; p++) {
        int q = (tid >> 3) + 32 * p;
        int jb = tid & 7;
        const uint32_t* src = &ot[q * 32 + ((jb ^ (q & 7)) << 2)];
        int4 w = *(const int4*)src;
        *(int4*)(Ob + ((size_t)b * TT + qb * 128 + q) * CC + h * HD + jb * 8) = w;
    }
}

// ---------------------------------------------------------------- launch
extern "C" void kernel_launch(void* const* d_in, const int* in_sizes, int n_in,
                              void* d_out, int out_size, void* d_ws, size_t ws_size,
                              hipStream_t stream) {
    const float* x     = (const float*)d_in[0];
    const float* Wqkv  = (const float*)d_in[1];
    const float* bqkv  = (const float*)d_in[2];
    const float* Wproj = (const float*)d_in[3];
    const float* bproj = (const float*)d_in[4];
    // d_in[5] = mask: causal by construction, unused

    char* ws = (char*)d_ws;
    // ws layout: WqkvT 3538944 | WprojT 1179648 | fc 262144 | Qb | Kb | V/Ob | VbT
    // V is dead after vtrans -> attn's O output reuses V's buffer.
    short*  WqkvT  = (short*)(ws);
    short*  WprojT = (short*)(ws + 3538944);
    float2* fc     = (float2*)(ws + 3538944 + 1179648);
    short*  Qb     = (short*)(ws + 4980736);
    short*  Kb     = (short*)(ws + 4980736 + 1 * 12582912);
    short*  VOb    = (short*)(ws + 4980736 + 2 * 12582912);  // V, then O after vtrans
    short*  VbT    = (short*)(ws + 4980736 + 3 * 12582912);
    float*  out    = (float*)d_out;

    hipLaunchKernelGGL(fc_kernel, dim3(128), dim3(256), 0, stream, fc);
    hipLaunchKernelGGL(transpose_cast_kernel, dim3(72, 24), dim3(32, 8), 0, stream,
                       Wqkv, WqkvT, 768, 2304);
    hipLaunchKernelGGL(transpose_cast_kernel, dim3(24, 24), dim3(32, 8), 0, stream,
                       Wproj, WprojT, 768, 768);
    hipLaunchKernelGGL((gemm_kernel<true, 0>), dim3(18, 64), dim3(256), 0, stream,
                       (const void*)x, WqkvT, bqkv, 768, Qb, Kb, VOb, fc, (float*)nullptr);
    hipLaunchKernelGGL(vtrans_kernel, dim3(16, 96), dim3(256), 0, stream, VOb, VbT);
    hipLaunchKernelGGL(attn_kernel, dim3(96, 8), dim3(256), 0, stream, Qb, Kb, VbT, VOb);
    hipLaunchKernelGGL((gemm_kernel<false, 1>), dim3(6, 64), dim3(256), 0, stream,
                       (const void*)VOb, WprojT, bproj, 768,
                       (short*)nullptr, (short*)nullptr, (short*)nullptr,
                       (const float2*)nullptr, out);
}

// Round 4
// 192.312 us; speedup vs baseline: 1.4295x; 1.0152x over previous
//
#include <hip/hip_runtime.h>
#include <cstdint>
#include <cstddef>

// Problem constants
#define BB 8
#define TT 1024
#define CC 768
#define NH 12
#define HD 64
// N of QKV gemm = 2304, K = 768 (both GEMMs K=768)

using bf16x8 = __attribute__((ext_vector_type(8))) short;  // 8 bf16 (4 VGPRs)
using f32x4  = __attribute__((ext_vector_type(4))) float;  // 4 fp32

static __device__ __forceinline__ short f2bf(float f) {
    uint32_t u;
    __builtin_memcpy(&u, &f, 4);
    u += 0x7FFFu + ((u >> 16) & 1u);   // RNE
    return (short)(u >> 16);
}

static __device__ __forceinline__ uint32_t bfpack(float lo, float hi) {
    return (uint32_t)(uint16_t)f2bf(lo) | ((uint32_t)(uint16_t)f2bf(hi) << 16);
}

#define GLOAD_LDS16(gp, lp)                                                        \
    __builtin_amdgcn_global_load_lds(                                              \
        (const __attribute__((address_space(1))) void*)(gp),                       \
        (__attribute__((address_space(3))) void*)(lp), 16, 0, 0)

// ---------------------------------------------------------------- fc table
__global__ void fc_kernel(float2* __restrict__ fc) {
    int idx = blockIdx.x * 256 + threadIdx.x;   // 32768 = 1024*32
    int t = idx >> 5, p = idx & 31;
    float freq = powf(10000.0f, -(float)p / 32.0f);
    float a = (float)t * freq;
    fc[idx] = make_float2(cosf(a), sinf(a));
}

// ---------------------------------------------------------------- x fp32 -> bf16
__global__ __launch_bounds__(256)
void cast_kernel(const float* __restrict__ in, short* __restrict__ out) {
    int i = (blockIdx.x * 256 + threadIdx.x) * 8;
    float4 f0 = *(const float4*)(in + i);
    float4 f1 = *(const float4*)(in + i + 4);
    bf16x8 h;
    h[0] = f2bf(f0.x); h[1] = f2bf(f0.y); h[2] = f2bf(f0.z); h[3] = f2bf(f0.w);
    h[4] = f2bf(f1.x); h[5] = f2bf(f1.y); h[6] = f2bf(f1.z); h[7] = f2bf(f1.w);
    *(bf16x8*)(out + i) = h;
}

// ------------------------------------------- transpose fp32 [R][C] -> bf16 [C][R]
__global__ __launch_bounds__(256)
void transpose_cast_kernel(const float* __restrict__ in, short* __restrict__ out,
                           int R, int Cdim) {
    __shared__ float tile[32][33];
    int tx = threadIdx.x, ty = threadIdx.y;
    int c0 = blockIdx.x * 32, r0 = blockIdx.y * 32;
#pragma unroll
    for (int i = 0; i < 4; i++)
        tile[ty + 8 * i][tx] = in[(size_t)(r0 + ty + 8 * i) * Cdim + c0 + tx];
    __syncthreads();
#pragma unroll
    for (int i = 0; i < 4; i++)
        out[(size_t)(c0 + ty + 8 * i) * R + r0 + tx] = f2bf(tile[tx][ty + 8 * i]);
}

// ------------------------------------------- V [bh][t][64] -> VT [bh][64][t] (bf16)
__global__ __launch_bounds__(256)
void vtrans_kernel(const short* __restrict__ V, short* __restrict__ VT) {
    __shared__ short tl[64][72];
    const int tid = threadIdx.x;
    const int bh = blockIdx.y, t0 = blockIdx.x * 64;
    {
        int r = tid >> 2, cs = (tid & 3) * 16;
        const short* src = V + (size_t)bh * TT * HD + (size_t)(t0 + r) * HD + cs;
        *(bf16x8*)&tl[r][cs]     = *(const bf16x8*)src;
        *(bf16x8*)&tl[r][cs + 8] = *(const bf16x8*)(src + 8);
    }
    __syncthreads();
    {
        int d = tid >> 2, ts = (tid & 3) * 16;
        bf16x8 o0, o1;
#pragma unroll
        for (int e = 0; e < 8; e++) { o0[e] = tl[ts + e][d]; o1[e] = tl[ts + 8 + e][d]; }
        short* dst = VT + (size_t)bh * TT * HD + (size_t)d * TT + t0 + ts;
        *(bf16x8*)dst       = o0;
        *(bf16x8*)(dst + 8) = o1;
    }
}

// ---------------------------------------------------------------- GEMM (m97 structure)
// C[M,N] = A[M,K] @ B[K,N] + bias; A bf16 [M][768], B pre-transposed bf16 BT[N][768].
// 128x128 tile, 4 waves (2x2), BK=64, global_load_lds width-16 staging into linear
// LDS, 2 barriers/K-step. Bijective XCD swizzle on block id.
// EPI 0: RoPE + scatter Q/K/V bf16 [B][H][T][HD] (Q pre-scaled 0.125) via 32KB LDS
//        repack -> 16B coalesced stores.
// EPI 1: fp32 out direct.
template <int EPI>
__global__ __launch_bounds__(256)
void gemm_kernel(const short* __restrict__ Agl, const short* __restrict__ BT,
                 const float* __restrict__ bias,
                 short* __restrict__ Qb, short* __restrict__ Kb, short* __restrict__ Vb,
                 const float2* __restrict__ fc, float* __restrict__ out) {
    __shared__ __align__(16) char smem[32768];
    short* As = (short*)smem;              // [128][64] bf16, linear
    short* Bs = (short*)(smem + 16384);    // [128][64] bf16, linear
    const int tid = threadIdx.x;
    const int lane = tid & 63, wid = tid >> 6;
    const int g = lane >> 4, c = lane & 15;
    const int wm = wid >> 1, wn = wid & 1;

    // XCD-aware bijective swizzle (nwg % 8 == 0 for both GEMMs)
    const int bid = blockIdx.y * gridDim.x + blockIdx.x;
    const int cpx = (gridDim.x * gridDim.y) >> 3;
    const int swz = (bid & 7) * cpx + (bid >> 3);
    const int m0 = (swz / gridDim.x) * 128, n0 = (swz % gridDim.x) * 128;

    const f32x4 zero4 = {0.f, 0.f, 0.f, 0.f};
    f32x4 acc[4][4];
#pragma unroll
    for (int i = 0; i < 4; i++)
#pragma unroll
        for (int j = 0; j < 4; j++) acc[i][j] = zero4;

    const int rowb = lane >> 3;        // 0..7 within 8-row chunk
    const int colb = (lane & 7) * 8;   // bf16 col within 64

    for (int k0 = 0; k0 < 768; k0 += 64) {
        const short* ga = Agl + (size_t)(m0 + wid * 32 + rowb) * 768 + k0 + colb;
        const short* gb = BT  + (size_t)(n0 + wid * 32 + rowb) * 768 + k0 + colb;
#pragma unroll
        for (int q = 0; q < 4; q++) {
            GLOAD_LDS16(ga + (size_t)q * 8 * 768, As + (wid * 32 + q * 8) * 64);
            GLOAD_LDS16(gb + (size_t)q * 8 * 768, Bs + (wid * 32 + q * 8) * 64);
        }
        __syncthreads();
#pragma unroll
        for (int kk = 0; kk < 2; kk++) {
            bf16x8 af[4], bfr[4];
#pragma unroll
            for (int mi = 0; mi < 4; mi++)
                af[mi] = *(const bf16x8*)&As[(wm * 64 + mi * 16 + c) * 64 + kk * 32 + g * 8];
#pragma unroll
            for (int ni = 0; ni < 4; ni++)
                bfr[ni] = *(const bf16x8*)&Bs[(wn * 64 + ni * 16 + c) * 64 + kk * 32 + g * 8];
#pragma unroll
            for (int mi = 0; mi < 4; mi++)
#pragma unroll
                for (int ni = 0; ni < 4; ni++)
                    acc[mi][ni] = __builtin_amdgcn_mfma_f32_16x16x32_bf16(
                        af[mi], bfr[ni], acc[mi][ni], 0, 0, 0);
        }
        __syncthreads();
    }

    if (EPI == 0) {
        // Phase 1: RoPE on (even,odd) col pairs, pack u32, write swizzled LDS C-tile.
        // LD[m][w] words (w = n/2), swizzle w' = w ^ (((m>>2)&3)<<3).
        uint32_t* LD = (uint32_t*)smem;   // [128][64] u32 = 32 KB (As/Bs dead)
#pragma unroll
        for (int ni = 0; ni < 4; ni++) {
            int nl = wn * 64 + ni * 16 + c;
            int n = n0 + nl;
            float bv = bias[n];
            int part = (n >= 1536) ? 2 : (n >= 768 ? 1 : 0);
            int d = (n - part * 768) & 63;
#pragma unroll
            for (int mi = 0; mi < 4; mi++) {
#pragma unroll
                for (int r = 0; r < 4; r++) {
                    int ml = wm * 64 + mi * 16 + g * 4 + r;
                    float v = acc[mi][ni][r] + bv;
                    float pv = __shfl_xor(v, 1);   // partner col n^1 (all lanes exec)
                    if (!(c & 1)) {
                        float o0, o1;
                        if (part < 2) {
                            int t = (m0 + ml) & 1023;
                            float2 cs = fc[t * 32 + (d >> 1)];
                            o0 = v * cs.x - pv * cs.y;
                            o1 = v * cs.y + pv * cs.x;
                            if (part == 0) { o0 *= 0.125f; o1 *= 0.125f; }
                        } else { o0 = v; o1 = pv; }
                        LD[ml * 64 + ((nl >> 1) ^ (((ml >> 2) & 3) << 3))] = bfpack(o0, o1);
                    }
                }
            }
        }
        __syncthreads();
        // Phase 2: coalesced 16B scatter stores.
#pragma unroll
        for (int p = 0; p < 8; p++) {
            int ml = p * 16 + (tid >> 4);
            int wc = (tid & 15) * 4;
            int4 dat = *(const int4*)&LD[ml * 64 + (wc ^ (((ml >> 2) & 3) << 3))];
            int n = n0 + wc * 2;
            int part = (n >= 1536) ? 2 : (n >= 768 ? 1 : 0);
            int rem = n - part * 768;
            int h = rem >> 6, d = rem & 63;
            int m = m0 + ml, b = m >> 10, t = m & 1023;
            short* dst = (part == 0 ? Qb : part == 1 ? Kb : Vb)
                         + (((size_t)b * NH + h) * TT + t) * HD + d;
            *(int4*)dst = dat;
        }
    } else {
#pragma unroll
        for (int mi = 0; mi < 4; mi++)
#pragma unroll
            for (int ni = 0; ni < 4; ni++) {
                int n = n0 + wn * 64 + ni * 16 + c;
                float bv = bias[n];
#pragma unroll
                for (int r = 0; r < 4; r++) {
                    int m = m0 + wm * 64 + mi * 16 + g * 4 + r;
                    out[(size_t)m * CC + n] = acc[mi][ni][r] + bv;
                }
            }
    }
}

// ---------------------------------------------------------------- flash attention
// (unchanged from round 3 — passed; swapped-operand S^T = mfma(K,Q), lane-local
// softmax, per-wave barrier-free LDS P-tile, V from global VT, LDS O^T epilogue)
__global__ __launch_bounds__(256)
void attn_kernel(const short* __restrict__ Qb, const short* __restrict__ Kb,
                 const short* __restrict__ VT, short* __restrict__ Ob) {
    __shared__ uint32_t Pt[4][32][32];  // 16 KB per-wave P tile, XOR-swizzled
    __shared__ uint32_t ot[128 * 32];   // 16 KB epilogue O^T transpose
    const int tid = threadIdx.x, lane = tid & 63, wid = tid >> 6;
    const int g = lane >> 4, c = lane & 15;
    const int bh = blockIdx.x, qb = 7 - (int)blockIdx.y;
    const int b = bh / NH, h = bh % NH;
    const short* Qp = Qb + (size_t)bh * TT * HD;
    const short* Kp = Kb + (size_t)bh * TT * HD;
    const short* Vp = VT + (size_t)bh * TT * HD;
    const int q0 = qb * 128 + wid * 32;
    const int sw = (c & 7) << 2;

    bf16x8 qf[2][2];
#pragma unroll
    for (int qs = 0; qs < 2; qs++)
#pragma unroll
        for (int kh = 0; kh < 2; kh++)
            qf[qs][kh] = *(const bf16x8*)(Qp + (size_t)(q0 + qs * 16 + c) * HD + kh * 32 + g * 8);

    const f32x4 zero4 = {0.f, 0.f, 0.f, 0.f};
    f32x4 o[2][4];
#pragma unroll
    for (int qs = 0; qs < 2; qs++)
#pragma unroll
        for (int dt = 0; dt < 4; dt++) o[qs][dt] = zero4;
    float mrun[2] = {-1e30f, -1e30f}, lrun[2] = {0.f, 0.f};

    const int t0max = ((q0 + 31) >> 6) << 6;
    for (int t0 = 0; t0 <= t0max; t0 += 64) {
        f32x4 st[2][4];
#pragma unroll
        for (int nt = 0; nt < 4; nt++) {
            const short* kp = Kp + (size_t)(t0 + nt * 16 + c) * HD + g * 8;
            bf16x8 k0 = *(const bf16x8*)kp;
            bf16x8 k1 = *(const bf16x8*)(kp + 32);
#pragma unroll
            for (int qs = 0; qs < 2; qs++) {
                f32x4 z = zero4;
                z = __builtin_amdgcn_mfma_f32_16x16x32_bf16(k0, qf[qs][0], z, 0, 0, 0);
                z = __builtin_amdgcn_mfma_f32_16x16x32_bf16(k1, qf[qs][1], z, 0, 0, 0);
                st[qs][nt] = z;
            }
        }
        bf16x8 vf[2][4];
#pragma unroll
        for (int blk = 0; blk < 2; blk++)
#pragma unroll
            for (int dt = 0; dt < 4; dt++)
                vf[blk][dt] = *(const bf16x8*)(Vp + (size_t)(dt * 16 + c) * TT + t0 + blk * 32 + g * 8);
        if (t0 + 63 > q0) {
#pragma unroll
            for (int qs = 0; qs < 2; qs++) {
                int q = q0 + qs * 16 + c;
#pragma unroll
                for (int nt = 0; nt < 4; nt++)
#pragma unroll
                    for (int r = 0; r < 4; r++)
                        if (t0 + nt * 16 + g * 4 + r > q) st[qs][nt][r] = -1e30f;
            }
        }
#pragma unroll
        for (int qs = 0; qs < 2; qs++) {
            float mx = st[qs][0][0];
#pragma unroll
            for (int nt = 0; nt < 4; nt++)
#pragma unroll
                for (int r = 0; r < 4; r++) mx = fmaxf(mx, st[qs][nt][r]);
            mx = fmaxf(mx, __shfl_xor(mx, 16));
            mx = fmaxf(mx, __shfl_xor(mx, 32));
            float mnew = fmaxf(mrun[qs], mx);
            float al = __expf(mrun[qs] - mnew);
            mrun[qs] = mnew;
            float sm = 0.f;
#pragma unroll
            for (int nt = 0; nt < 4; nt++)
#pragma unroll
                for (int r = 0; r < 4; r++) {
                    float e = __expf(st[qs][nt][r] - mnew);
                    st[qs][nt][r] = e;
                    sm += e;
                }
            sm += __shfl_xor(sm, 16);
            sm += __shfl_xor(sm, 32);
            lrun[qs] = lrun[qs] * al + sm;
#pragma unroll
            for (int dt = 0; dt < 4; dt++) {
                o[qs][dt][0] *= al; o[qs][dt][1] *= al;
                o[qs][dt][2] *= al; o[qs][dt][3] *= al;
            }
            int row = qs * 16 + c;
#pragma unroll
            for (int nt = 0; nt < 4; nt++) {
                uint32_t w0 = bfpack(st[qs][nt][0], st[qs][nt][1]);
                uint32_t w1 = bfpack(st[qs][nt][2], st[qs][nt][3]);
                int wa = nt * 8 + 2 * g;
                Pt[wid][row][wa ^ sw]       = w0;
                Pt[wid][row][(wa + 1) ^ sw] = w1;
            }
        }
#pragma unroll
        for (int qs = 0; qs < 2; qs++) {
            int row = qs * 16 + c;
#pragma unroll
            for (int blk = 0; blk < 2; blk++) {
                bf16x8 pf = *(const bf16x8*)&Pt[wid][row][(blk * 16 + 4 * g) ^ sw];
#pragma unroll
                for (int dt = 0; dt < 4; dt++)
                    o[qs][dt] = __builtin_amdgcn_mfma_f32_16x16x32_bf16(
                        vf[blk][dt], pf, o[qs][dt], 0, 0, 0);
            }
        }
    }

#pragma unroll
    for (int qs = 0; qs < 2; qs++) {
        float inv = 1.0f / lrun[qs];
        int ql = wid * 32 + qs * 16 + c;
#pragma unroll
        for (int dt = 0; dt < 4; dt++) {
            uint32_t w0 = bfpack(o[qs][dt][0] * inv, o[qs][dt][1] * inv);
            uint32_t w1 = bfpack(o[qs][dt][2] * inv, o[qs][dt][3] * inv);
            int jc0 = dt * 8 + 2 * g;
            int jc1 = jc0 + 1;
            ot[ql * 32 + ((((jc0 >> 2) ^ (c & 7)) << 2) | (jc0 & 3))] = w0;
            ot[ql * 32 + ((((jc1 >> 2) ^ (c & 7)) << 2) | (jc1 & 3))] = w1;
        }
    }
    __syncthreads();
#pragma unroll
    for (int p = 0; p < 4; p++) {
        int q = (tid >> 3) + 32 * p;
        int jb = tid & 7;
        const uint32_t* src = &ot[q * 32 + ((jb ^ (q & 7)) << 2)];
        int4 w = *(const int4*)src;
        *(int4*)(Ob + ((size_t)b * TT + qb * 128 + q) * CC + h * HD + jb * 8) = w;
    }
}

// ---------------------------------------------------------------- launch
extern "C" void kernel_launch(void* const* d_in, const int* in_sizes, int n_in,
                              void* d_out, int out_size, void* d_ws, size_t ws_size,
                              hipStream_t stream) {
    const float* x     = (const float*)d_in[0];
    const float* Wqkv  = (const float*)d_in[1];
    const float* bqkv  = (const float*)d_in[2];
    const float* Wproj = (const float*)d_in[3];
    const float* bproj = (const float*)d_in[4];
    // d_in[5] = mask: causal by construction, unused

    char* ws = (char*)d_ws;
    // ws layout: WqkvT 3538944 | WprojT 1179648 | fc 262144 | Qb | Kb | V/Ob | VbT
    // xb (bf16 x) ALIASES VbT: xb consumed by gemm1, VbT written later by vtrans.
    short*  WqkvT  = (short*)(ws);
    short*  WprojT = (short*)(ws + 3538944);
    float2* fc     = (float2*)(ws + 3538944 + 1179648);
    short*  Qb     = (short*)(ws + 4980736);
    short*  Kb     = (short*)(ws + 4980736 + 1 * 12582912);
    short*  VOb    = (short*)(ws + 4980736 + 2 * 12582912);  // V, then O after vtrans
    short*  VbT    = (short*)(ws + 4980736 + 3 * 12582912);
    short*  xb     = VbT;
    float*  out    = (float*)d_out;

    hipLaunchKernelGGL(fc_kernel, dim3(128), dim3(256), 0, stream, fc);
    hipLaunchKernelGGL(transpose_cast_kernel, dim3(72, 24), dim3(32, 8), 0, stream,
                       Wqkv, WqkvT, 768, 2304);
    hipLaunchKernelGGL(transpose_cast_kernel, dim3(24, 24), dim3(32, 8), 0, stream,
                       Wproj, WprojT, 768, 768);
    hipLaunchKernelGGL(cast_kernel, dim3(3072), dim3(256), 0, stream, x, xb);
    hipLaunchKernelGGL((gemm_kernel<0>), dim3(18, 64), dim3(256), 0, stream,
                       xb, WqkvT, bqkv, Qb, Kb, VOb, fc, (float*)nullptr);
    hipLaunchKernelGGL(vtrans_kernel, dim3(16, 96), dim3(256), 0, stream, VOb, VbT);
    hipLaunchKernelGGL(attn_kernel, dim3(96, 8), dim3(256), 0, stream, Qb, Kb, VbT, VOb);
    hipLaunchKernelGGL((gemm_kernel<1>), dim3(6, 64), dim3(256), 0, stream,
                       VOb, WprojT, bproj,
                       (short*)nullptr, (short*)nullptr, (short*)nullptr,
                       (const float2*)nullptr, out);
}

// Round 5
// 173.495 us; speedup vs baseline: 1.5845x; 1.1085x over previous
//
#include <hip/hip_runtime.h>
#include <cstdint>
#include <cstddef>

// Problem constants
#define BB 8
#define TT 1024
#define CC 768
#define NH 12
#define HD 64
// GEMM1: M=8192 N=2304 K=768.  GEMM2: M=8192 N=768 K=768.

using bf16x8 = __attribute__((ext_vector_type(8))) short;  // 8 bf16 (4 VGPRs)
using f32x4  = __attribute__((ext_vector_type(4))) float;  // 4 fp32

static __device__ __forceinline__ short f2bf(float f) {
    uint32_t u;
    __builtin_memcpy(&u, &f, 4);
    u += 0x7FFFu + ((u >> 16) & 1u);   // RNE
    return (short)(u >> 16);
}

static __device__ __forceinline__ uint32_t bfpack(float lo, float hi) {
    return (uint32_t)(uint16_t)f2bf(lo) | ((uint32_t)(uint16_t)f2bf(hi) << 16);
}

#define GLOAD_LDS16(gp, lp)                                                        \
    __builtin_amdgcn_global_load_lds(                                              \
        (const __attribute__((address_space(1))) void*)(gp),                       \
        (__attribute__((address_space(3))) void*)(lp), 16, 0, 0)

// ---------------------------------------------------------------- fc table
__global__ void fc_kernel(float2* __restrict__ fc) {
    int idx = blockIdx.x * 256 + threadIdx.x;   // 32768 = 1024*32
    int t = idx >> 5, p = idx & 31;
    float freq = powf(10000.0f, -(float)p / 32.0f);
    float a = (float)t * freq;
    fc[idx] = make_float2(cosf(a), sinf(a));
}

// ---------------------------------------------------------------- x fp32 -> bf16
__global__ __launch_bounds__(256)
void cast_kernel(const float* __restrict__ in, short* __restrict__ out) {
    int i = (blockIdx.x * 256 + threadIdx.x) * 8;
    float4 f0 = *(const float4*)(in + i);
    float4 f1 = *(const float4*)(in + i + 4);
    bf16x8 h;
    h[0] = f2bf(f0.x); h[1] = f2bf(f0.y); h[2] = f2bf(f0.z); h[3] = f2bf(f0.w);
    h[4] = f2bf(f1.x); h[5] = f2bf(f1.y); h[6] = f2bf(f1.z); h[7] = f2bf(f1.w);
    *(bf16x8*)(out + i) = h;
}

// ------------------------------------------- transpose fp32 [R][C] -> bf16 [C][R]
__global__ __launch_bounds__(256)
void transpose_cast_kernel(const float* __restrict__ in, short* __restrict__ out,
                           int R, int Cdim) {
    __shared__ float tile[32][33];
    int tx = threadIdx.x, ty = threadIdx.y;
    int c0 = blockIdx.x * 32, r0 = blockIdx.y * 32;
#pragma unroll
    for (int i = 0; i < 4; i++)
        tile[ty + 8 * i][tx] = in[(size_t)(r0 + ty + 8 * i) * Cdim + c0 + tx];
    __syncthreads();
#pragma unroll
    for (int i = 0; i < 4; i++)
        out[(size_t)(c0 + ty + 8 * i) * R + r0 + tx] = f2bf(tile[tx][ty + 8 * i]);
}

// ------------------------------------------- V [bh][t][64] -> VT [bh][64][t] (bf16)
__global__ __launch_bounds__(256)
void vtrans_kernel(const short* __restrict__ V, short* __restrict__ VT) {
    __shared__ short tl[64][72];
    const int tid = threadIdx.x;
    const int bh = blockIdx.y, t0 = blockIdx.x * 64;
    {
        int r = tid >> 2, cs = (tid & 3) * 16;
        const short* src = V + (size_t)bh * TT * HD + (size_t)(t0 + r) * HD + cs;
        *(bf16x8*)&tl[r][cs]     = *(const bf16x8*)src;
        *(bf16x8*)&tl[r][cs + 8] = *(const bf16x8*)(src + 8);
    }
    __syncthreads();
    {
        int d = tid >> 2, ts = (tid & 3) * 16;
        bf16x8 o0, o1;
#pragma unroll
        for (int e = 0; e < 8; e++) { o0[e] = tl[ts + e][d]; o1[e] = tl[ts + 8 + e][d]; }
        short* dst = VT + (size_t)bh * TT * HD + (size_t)d * TT + t0 + ts;
        *(bf16x8*)dst       = o0;
        *(bf16x8*)(dst + 8) = o1;
    }
}

// ---------------------------------------------------------------- pipelined GEMM
// C[M,N] = A[M,768] @ B + bias; B pre-transposed bf16 BT[N][768].
// BM=128, BN=256, BK=64 (2 k-half phases of K=32), 512 threads = 8 waves (2M x 4N),
// wave tile 64x64. LDS 96 KB: 2 dbuf x {A[128][32] x2 kh, B[256][32] x2 kh},
// XOR-swizzled via pre-swizzled global source (rule #21: swizzle source AND read).
// Counted vmcnt(6) pipeline (T3/T4), setprio around MFMA (T5), raw s_barrier.
// Rolling staging: P1(t) stages k1(t+1); P2(t) stages k0(t+2).
// EPI 0: RoPE + scatter Q/K/V via 64KB LDS repack -> 16B coalesced stores.
// EPI 1: fp32 out direct.
template <int EPI>
__global__ __launch_bounds__(512)
void gemm_kernel(const short* __restrict__ Agl, const short* __restrict__ BT,
                 const float* __restrict__ bias,
                 short* __restrict__ Qb, short* __restrict__ Kb, short* __restrict__ Vb,
                 const float2* __restrict__ fc, float* __restrict__ out) {
    __shared__ __align__(16) char smem[98304];   // 96 KB
    const int tid = threadIdx.x;
    const int lane = tid & 63, wid = tid >> 6;
    const int g = lane >> 4, c = lane & 15;
    const int wm = wid >> 2, wn = wid & 3;       // 2 x 4 wave grid

    // bijective XCD swizzle (nwg % 8 == 0: 576 and 192)
    const int nx = gridDim.x;
    const int bid = blockIdx.y * nx + blockIdx.x;
    const int cpx = (nx * gridDim.y) >> 3;
    const int swz = (bid & 7) * cpx + (bid >> 3);
    const int m0 = (swz / nx) * 128, n0 = (swz % nx) * 256;

    // staging thread mapping (pre-swizzled global col-block)
    const int srow = tid >> 2;                   // 0..127
    const int sblk = tid & 3;
    const int scol0 = ((sblk ^ ((srow >> 1) & 3)) << 3);   // bf16 col within 32

    const short* Abase = Agl + (size_t)(m0 + srow) * 768 + scol0;
    const short* Bbase0 = BT + (size_t)(n0 + srow) * 768 + scol0;
    const short* Bbase1 = BT + (size_t)(n0 + 128 + srow) * 768 + scol0;

    // LDS slot offsets (bytes): per dbuf 48 KB: A kh0 @0, A kh1 @8192,
    // B kh0 @16384, B kh1 @32768. Wave-uniform dest + HW lane*16.
#define A_SLOT(b, kh) (smem + (b) * 49152 + (kh) * 8192 + wid * 1024)
#define B_SLOT(b, kh, q) (smem + (b) * 49152 + 16384 + (kh) * 16384 + (q) * 8192 + wid * 1024)
#define STAGE(b, kh, kt)                                                   \
    {                                                                      \
        int koff = (kt) * 64 + (kh) * 32;                                  \
        GLOAD_LDS16(Abase + koff, A_SLOT(b, kh));                          \
        GLOAD_LDS16(Bbase0 + koff, B_SLOT(b, kh, 0));                      \
        GLOAD_LDS16(Bbase1 + koff, B_SLOT(b, kh, 1));                      \
    }

    const f32x4 zero4 = {0.f, 0.f, 0.f, 0.f};
    f32x4 acc[4][4];
#pragma unroll
    for (int i = 0; i < 4; i++)
#pragma unroll
        for (int j = 0; j < 4; j++) acc[i][j] = zero4;

    // prologue: tile0 (k0,k1) + tile1 k0 = 9 loads
    STAGE(0, 0, 0);
    STAGE(0, 1, 0);
    STAGE(1, 0, 1);
    asm volatile("s_waitcnt vmcnt(6)" ::: "memory");
    __builtin_amdgcn_s_barrier();

    for (int t = 0; t < 12; t++) {
        const int buf = t & 1;
        const int t1 = (t + 1 < 12) ? t + 1 : t - 11;
        const int t2 = (t + 2 < 12) ? t + 2 : t - 10;
#pragma unroll
        for (int kk = 0; kk < 2; kk++) {
            // ds-read this phase's fragments (2-way-free swizzled)
            const short* Ab = (const short*)(smem + buf * 49152 + kk * 8192);
            const short* Bb = (const short*)(smem + buf * 49152 + 16384 + kk * 16384);
            bf16x8 af[4], bfr[4];
#pragma unroll
            for (int mi = 0; mi < 4; mi++) {
                int row = wm * 64 + mi * 16 + c;
                af[mi] = *(const bf16x8*)&Ab[row * 32 + ((g ^ ((row >> 1) & 3)) << 3)];
            }
#pragma unroll
            for (int ni = 0; ni < 4; ni++) {
                int row = wn * 64 + ni * 16 + c;
                bfr[ni] = *(const bf16x8*)&Bb[row * 32 + ((g ^ ((row >> 1) & 3)) << 3)];
            }
            // rolling prefetch: P1 -> k1(t+1) into buf^1; P2 -> k0(t+2) into buf
            if (kk == 0) STAGE(buf ^ 1, 1, t1)
            else         STAGE(buf, 0, t2)
            __builtin_amdgcn_s_barrier();
            __builtin_amdgcn_s_setprio(1);
#pragma unroll
            for (int mi = 0; mi < 4; mi++)
#pragma unroll
                for (int ni = 0; ni < 4; ni++)
                    acc[mi][ni] = __builtin_amdgcn_mfma_f32_16x16x32_bf16(
                        af[mi], bfr[ni], acc[mi][ni], 0, 0, 0);
            __builtin_amdgcn_s_setprio(0);
            asm volatile("s_waitcnt vmcnt(6)" ::: "memory");
            __builtin_amdgcn_s_barrier();
        }
    }

    if (EPI == 0) {
        // drain wrap-staged loads before reusing LDS
        asm volatile("s_waitcnt vmcnt(0)" ::: "memory");
        __builtin_amdgcn_s_barrier();
        // Phase 1: RoPE on (even,odd) col pairs -> swizzled LDS [128][128 words]
        uint32_t* LD = (uint32_t*)smem;   // 64 KB
#pragma unroll
        for (int ni = 0; ni < 4; ni++) {
            int nl = wn * 64 + ni * 16 + c;
            int n = n0 + nl;
            float bv = bias[n];
            int part = (n >= 1536) ? 2 : (n >= 768 ? 1 : 0);
            int d = (n - part * 768) & 63;
#pragma unroll
            for (int mi = 0; mi < 4; mi++) {
#pragma unroll
                for (int r = 0; r < 4; r++) {
                    int ml = wm * 64 + mi * 16 + g * 4 + r;
                    float v = acc[mi][ni][r] + bv;
                    float pv = __shfl_xor(v, 1);   // partner col n^1 (all lanes exec)
                    if (!(c & 1)) {
                        float o0, o1;
                        if (part < 2) {
                            int t = (m0 + ml) & 1023;
                            float2 cs = fc[t * 32 + (d >> 1)];
                            o0 = v * cs.x - pv * cs.y;
                            o1 = v * cs.y + pv * cs.x;
                            if (part == 0) { o0 *= 0.125f; o1 *= 0.125f; }
                        } else { o0 = v; o1 = pv; }
                        LD[ml * 128 + ((nl >> 1) ^ (((ml >> 2) & 3) << 3))] = bfpack(o0, o1);
                    }
                }
            }
        }
        __syncthreads();
        // Phase 2: coalesced 16B scatter stores (8 passes x 16 rows)
#pragma unroll
        for (int p = 0; p < 8; p++) {
            int ml = p * 16 + (tid >> 5);
            int wg = tid & 31;
            int4 dat = *(const int4*)&LD[ml * 128 + ((wg * 4) ^ (((ml >> 2) & 3) << 3))];
            int n = n0 + wg * 8;
            int part = (n >= 1536) ? 2 : (n >= 768 ? 1 : 0);
            int rem = n - part * 768;
            int h = rem >> 6, d = rem & 63;
            int m = m0 + ml, b = m >> 10, t = m & 1023;
            short* dst = (part == 0 ? Qb : part == 1 ? Kb : Vb)
                         + (((size_t)b * NH + h) * TT + t) * HD + d;
            *(int4*)dst = dat;
        }
    } else {
#pragma unroll
        for (int mi = 0; mi < 4; mi++)
#pragma unroll
            for (int ni = 0; ni < 4; ni++) {
                int n = n0 + wn * 64 + ni * 16 + c;
                float bv = bias[n];
#pragma unroll
                for (int r = 0; r < 4; r++) {
                    int m = m0 + wm * 64 + mi * 16 + g * 4 + r;
                    out[(size_t)m * CC + n] = acc[mi][ni][r] + bv;
                }
            }
    }
#undef A_SLOT
#undef B_SLOT
#undef STAGE
}

// ---------------------------------------------------------------- flash attention
// (unchanged from round 3 — passed twice; swapped-operand S^T = mfma(K,Q), lane-local
// softmax, per-wave barrier-free LDS P-tile, V from global VT, LDS O^T epilogue)
__global__ __launch_bounds__(256)
void attn_kernel(const short* __restrict__ Qb, const short* __restrict__ Kb,
                 const short* __restrict__ VT, short* __restrict__ Ob) {
    __shared__ uint32_t Pt[4][32][32];  // 16 KB per-wave P tile, XOR-swizzled
    __shared__ uint32_t ot[128 * 32];   // 16 KB epilogue O^T transpose
    const int tid = threadIdx.x, lane = tid & 63, wid = tid >> 6;
    const int g = lane >> 4, c = lane & 15;
    const int bh = blockIdx.x, qb = 7 - (int)blockIdx.y;
    const int b = bh / NH, h = bh % NH;
    const short* Qp = Qb + (size_t)bh * TT * HD;
    const short* Kp = Kb + (size_t)bh * TT * HD;
    const short* Vp = VT + (size_t)bh * TT * HD;
    const int q0 = qb * 128 + wid * 32;
    const int sw = (c & 7) << 2;

    bf16x8 qf[2][2];
#pragma unroll
    for (int qs = 0; qs < 2; qs++)
#pragma unroll
        for (int kh = 0; kh < 2; kh++)
            qf[qs][kh] = *(const bf16x8*)(Qp + (size_t)(q0 + qs * 16 + c) * HD + kh * 32 + g * 8);

    const f32x4 zero4 = {0.f, 0.f, 0.f, 0.f};
    f32x4 o[2][4];
#pragma unroll
    for (int qs = 0; qs < 2; qs++)
#pragma unroll
        for (int dt = 0; dt < 4; dt++) o[qs][dt] = zero4;
    float mrun[2] = {-1e30f, -1e30f}, lrun[2] = {0.f, 0.f};

    const int t0max = ((q0 + 31) >> 6) << 6;
    for (int t0 = 0; t0 <= t0max; t0 += 64) {
        f32x4 st[2][4];
#pragma unroll
        for (int nt = 0; nt < 4; nt++) {
            const short* kp = Kp + (size_t)(t0 + nt * 16 + c) * HD + g * 8;
            bf16x8 k0 = *(const bf16x8*)kp;
            bf16x8 k1 = *(const bf16x8*)(kp + 32);
#pragma unroll
            for (int qs = 0; qs < 2; qs++) {
                f32x4 z = zero4;
                z = __builtin_amdgcn_mfma_f32_16x16x32_bf16(k0, qf[qs][0], z, 0, 0, 0);
                z = __builtin_amdgcn_mfma_f32_16x16x32_bf16(k1, qf[qs][1], z, 0, 0, 0);
                st[qs][nt] = z;
            }
        }
        bf16x8 vf[2][4];
#pragma unroll
        for (int blk = 0; blk < 2; blk++)
#pragma unroll
            for (int dt = 0; dt < 4; dt++)
                vf[blk][dt] = *(const bf16x8*)(Vp + (size_t)(dt * 16 + c) * TT + t0 + blk * 32 + g * 8);
        if (t0 + 63 > q0) {
#pragma unroll
            for (int qs = 0; qs < 2; qs++) {
                int q = q0 + qs * 16 + c;
#pragma unroll
                for (int nt = 0; nt < 4; nt++)
#pragma unroll
                    for (int r = 0; r < 4; r++)
                        if (t0 + nt * 16 + g * 4 + r > q) st[qs][nt][r] = -1e30f;
            }
        }
#pragma unroll
        for (int qs = 0; qs < 2; qs++) {
            float mx = st[qs][0][0];
#pragma unroll
            for (int nt = 0; nt < 4; nt++)
#pragma unroll
                for (int r = 0; r < 4; r++) mx = fmaxf(mx, st[qs][nt][r]);
            mx = fmaxf(mx, __shfl_xor(mx, 16));
            mx = fmaxf(mx, __shfl_xor(mx, 32));
            float mnew = fmaxf(mrun[qs], mx);
            float al = __expf(mrun[qs] - mnew);
            mrun[qs] = mnew;
            float sm = 0.f;
#pragma unroll
            for (int nt = 0; nt < 4; nt++)
#pragma unroll
                for (int r = 0; r < 4; r++) {
                    float e = __expf(st[qs][nt][r] - mnew);
                    st[qs][nt][r] = e;
                    sm += e;
                }
            sm += __shfl_xor(sm, 16);
            sm += __shfl_xor(sm, 32);
            lrun[qs] = lrun[qs] * al + sm;
#pragma unroll
            for (int dt = 0; dt < 4; dt++) {
                o[qs][dt][0] *= al; o[qs][dt][1] *= al;
                o[qs][dt][2] *= al; o[qs][dt][3] *= al;
            }
            int row = qs * 16 + c;
#pragma unroll
            for (int nt = 0; nt < 4; nt++) {
                uint32_t w0 = bfpack(st[qs][nt][0], st[qs][nt][1]);
                uint32_t w1 = bfpack(st[qs][nt][2], st[qs][nt][3]);
                int wa = nt * 8 + 2 * g;
                Pt[wid][row][wa ^ sw]       = w0;
                Pt[wid][row][(wa + 1) ^ sw] = w1;
            }
        }
#pragma unroll
        for (int qs = 0; qs < 2; qs++) {
            int row = qs * 16 + c;
#pragma unroll
            for (int blk = 0; blk < 2; blk++) {
                bf16x8 pf = *(const bf16x8*)&Pt[wid][row][(blk * 16 + 4 * g) ^ sw];
#pragma unroll
                for (int dt = 0; dt < 4; dt++)
                    o[qs][dt] = __builtin_amdgcn_mfma_f32_16x16x32_bf16(
                        vf[blk][dt], pf, o[qs][dt], 0, 0, 0);
            }
        }
    }

#pragma unroll
    for (int qs = 0; qs < 2; qs++) {
        float inv = 1.0f / lrun[qs];
        int ql = wid * 32 + qs * 16 + c;
#pragma unroll
        for (int dt = 0; dt < 4; dt++) {
            uint32_t w0 = bfpack(o[qs][dt][0] * inv, o[qs][dt][1] * inv);
            uint32_t w1 = bfpack(o[qs][dt][2] * inv, o[qs][dt][3] * inv);
            int jc0 = dt * 8 + 2 * g;
            int jc1 = jc0 + 1;
            ot[ql * 32 + ((((jc0 >> 2) ^ (c & 7)) << 2) | (jc0 & 3))] = w0;
            ot[ql * 32 + ((((jc1 >> 2) ^ (c & 7)) << 2) | (jc1 & 3))] = w1;
        }
    }
    __syncthreads();
#pragma unroll
    for (int p = 0; p < 4; p++) {
        int q = (tid >> 3) + 32 * p;
        int jb = tid & 7;
        const uint32_t* src = &ot[q * 32 + ((jb ^ (q & 7)) << 2)];
        int4 w = *(const int4*)src;
        *(int4*)(Ob + ((size_t)b * TT + qb * 128 + q) * CC + h * HD + jb * 8) = w;
    }
}

// ---------------------------------------------------------------- launch
extern "C" void kernel_launch(void* const* d_in, const int* in_sizes, int n_in,
                              void* d_out, int out_size, void* d_ws, size_t ws_size,
                              hipStream_t stream) {
    const float* x     = (const float*)d_in[0];
    const float* Wqkv  = (const float*)d_in[1];
    const float* bqkv  = (const float*)d_in[2];
    const float* Wproj = (const float*)d_in[3];
    const float* bproj = (const float*)d_in[4];
    // d_in[5] = mask: causal by construction, unused

    char* ws = (char*)d_ws;
    // ws layout: WqkvT 3538944 | WprojT 1179648 | fc 262144 | Qb | Kb | V/Ob | VbT
    // xb (bf16 x) ALIASES VbT: xb consumed by gemm1, VbT written later by vtrans.
    short*  WqkvT  = (short*)(ws);
    short*  WprojT = (short*)(ws + 3538944);
    float2* fc     = (float2*)(ws + 3538944 + 1179648);
    short*  Qb     = (short*)(ws + 4980736);
    short*  Kb     = (short*)(ws + 4980736 + 1 * 12582912);
    short*  VOb    = (short*)(ws + 4980736 + 2 * 12582912);  // V, then O after vtrans
    short*  VbT    = (short*)(ws + 4980736 + 3 * 12582912);
    short*  xb     = VbT;
    float*  out    = (float*)d_out;

    hipLaunchKernelGGL(fc_kernel, dim3(128), dim3(256), 0, stream, fc);
    hipLaunchKernelGGL(transpose_cast_kernel, dim3(72, 24), dim3(32, 8), 0, stream,
                       Wqkv, WqkvT, 768, 2304);
    hipLaunchKernelGGL(transpose_cast_kernel, dim3(24, 24), dim3(32, 8), 0, stream,
                       Wproj, WprojT, 768, 768);
    hipLaunchKernelGGL(cast_kernel, dim3(3072), dim3(256), 0, stream, x, xb);
    hipLaunchKernelGGL((gemm_kernel<0>), dim3(9, 64), dim3(512), 0, stream,
                       xb, WqkvT, bqkv, Qb, Kb, VOb, fc, (float*)nullptr);
    hipLaunchKernelGGL(vtrans_kernel, dim3(16, 96), dim3(256), 0, stream, VOb, VbT);
    hipLaunchKernelGGL(attn_kernel, dim3(96, 8), dim3(256), 0, stream, Qb, Kb, VbT, VOb);
    hipLaunchKernelGGL((gemm_kernel<1>), dim3(3, 64), dim3(512), 0, stream,
                       VOb, WprojT, bproj,
                       (short*)nullptr, (short*)nullptr, (short*)nullptr,
                       (const float2*)nullptr, out);
}

// Round 7
// 169.328 us; speedup vs baseline: 1.6235x; 1.0246x over previous
//
#include <hip/hip_runtime.h>
#include <cstdint>
#include <cstddef>

// Problem constants
#define BB 8
#define TT 1024
#define CC 768
#define NH 12
#define HD 64
// GEMM1: M=8192 N=2304 K=768.  GEMM2: M=8192 N=768 K=768.

using bf16x8 = __attribute__((ext_vector_type(8))) short;  // 8 bf16 (4 VGPRs)
using f32x4  = __attribute__((ext_vector_type(4))) float;  // 4 fp32

static __device__ __forceinline__ short f2bf(float f) {
    uint32_t u;
    __builtin_memcpy(&u, &f, 4);
    u += 0x7FFFu + ((u >> 16) & 1u);   // RNE
    return (short)(u >> 16);
}

static __device__ __forceinline__ uint32_t bfpack(float lo, float hi) {
    return (uint32_t)(uint16_t)f2bf(lo) | ((uint32_t)(uint16_t)f2bf(hi) << 16);
}

#define GLOAD_LDS16(gp, lp)                                                        \
    __builtin_amdgcn_global_load_lds(                                              \
        (const __attribute__((address_space(1))) void*)(gp),                       \
        (__attribute__((address_space(3))) void*)(lp), 16, 0, 0)

// ---------------------------------------------------------------- fc table
__global__ void fc_kernel(float2* __restrict__ fc) {
    int idx = blockIdx.x * 256 + threadIdx.x;   // 32768 = 1024*32
    int t = idx >> 5, p = idx & 31;
    float freq = powf(10000.0f, -(float)p / 32.0f);
    float a = (float)t * freq;
    fc[idx] = make_float2(cosf(a), sinf(a));
}

// ---------------------------------------------------------------- x fp32 -> bf16
__global__ __launch_bounds__(256)
void cast_kernel(const float* __restrict__ in, short* __restrict__ out) {
    int i = (blockIdx.x * 256 + threadIdx.x) * 8;
    float4 f0 = *(const float4*)(in + i);
    float4 f1 = *(const float4*)(in + i + 4);
    bf16x8 h;
    h[0] = f2bf(f0.x); h[1] = f2bf(f0.y); h[2] = f2bf(f0.z); h[3] = f2bf(f0.w);
    h[4] = f2bf(f1.x); h[5] = f2bf(f1.y); h[6] = f2bf(f1.z); h[7] = f2bf(f1.w);
    *(bf16x8*)(out + i) = h;
}

// ------------------------------------------- transpose fp32 [R][C] -> bf16 [C][R]
__global__ __launch_bounds__(256)
void transpose_cast_kernel(const float* __restrict__ in, short* __restrict__ out,
                           int R, int Cdim) {
    __shared__ float tile[32][33];
    int tx = threadIdx.x, ty = threadIdx.y;
    int c0 = blockIdx.x * 32, r0 = blockIdx.y * 32;
#pragma unroll
    for (int i = 0; i < 4; i++)
        tile[ty + 8 * i][tx] = in[(size_t)(r0 + ty + 8 * i) * Cdim + c0 + tx];
    __syncthreads();
#pragma unroll
    for (int i = 0; i < 4; i++)
        out[(size_t)(c0 + ty + 8 * i) * R + r0 + tx] = f2bf(tile[tx][ty + 8 * i]);
}

// ------------------------------------------- V [bh][t][64] -> VT [bh][64][t] (bf16)
__global__ __launch_bounds__(256)
void vtrans_kernel(const short* __restrict__ V, short* __restrict__ VT) {
    __shared__ short tl[64][72];
    const int tid = threadIdx.x;
    const int bh = blockIdx.y, t0 = blockIdx.x * 64;
    {
        int r = tid >> 2, cs = (tid & 3) * 16;
        const short* src = V + (size_t)bh * TT * HD + (size_t)(t0 + r) * HD + cs;
        *(bf16x8*)&tl[r][cs]     = *(const bf16x8*)src;
        *(bf16x8*)&tl[r][cs + 8] = *(const bf16x8*)(src + 8);
    }
    __syncthreads();
    {
        int d = tid >> 2, ts = (tid & 3) * 16;
        bf16x8 o0, o1;
#pragma unroll
        for (int e = 0; e < 8; e++) { o0[e] = tl[ts + e][d]; o1[e] = tl[ts + 8 + e][d]; }
        short* dst = VT + (size_t)bh * TT * HD + (size_t)d * TT + t0 + ts;
        *(bf16x8*)dst       = o0;
        *(bf16x8*)(dst + 8) = o1;
    }
}

// ---------------------------------------------------------------- pipelined GEMM
// Identical to round 6 EXCEPT: the vmcnt(0)+barrier drain now runs for BOTH
// epilogue paths. Round-6 race: EPI1 ended waves with in-flight global_load_lds
// DMAs; a new block allocated the same LDS slot got its staged tiles corrupted
// (needed 2-resident blocks to manifest — r5's 192-block GEMM2 never reused slots).
template <int EPI>
__global__ __launch_bounds__(256)
void gemm_kernel(const short* __restrict__ Agl, const short* __restrict__ BT,
                 const float* __restrict__ bias,
                 short* __restrict__ Qb, short* __restrict__ Kb, short* __restrict__ Vb,
                 const float2* __restrict__ fc, float* __restrict__ out) {
    __shared__ __align__(16) char smem[65536];   // 64 KB
    const int tid = threadIdx.x;
    const int lane = tid & 63, wid = tid >> 6;
    const int g = lane >> 4, c = lane & 15;
    const int wm = wid >> 1, wn = wid & 1;       // 2 x 2 wave grid

    // bijective XCD swizzle (nwg % 8 == 0: 1152 and 384)
    const int nx = gridDim.x;
    const int bid = blockIdx.y * nx + blockIdx.x;
    const int cpx = (nx * gridDim.y) >> 3;
    const int swz = (bid & 7) * cpx + (bid >> 3);
    const int m0 = (swz / nx) * 128, n0 = (swz % nx) * 128;

    // staging mapping: instruction (matrix, q) covers rows wid*32+q*16+(lane>>2),
    // 16B col-chunk (lane&3), with XOR source-swizzle (chunk ^ ((row>>1)&3)).
    const int sr = lane >> 2;                       // 0..15
    const int scol = (((lane & 3) ^ ((sr >> 1) & 3)) << 3);  // bf16 col in 32
    const short* Abase = Agl + (size_t)(m0 + wid * 32 + sr) * 768 + scol;
    const short* Bbase = BT  + (size_t)(n0 + wid * 32 + sr) * 768 + scol;

    // LDS (bytes): per dbuf 32 KB: Akh0 @0 | Akh1 @8192 | Bkh0 @16384 | Bkh1 @24576.
#define A_SLOT(b, kh, q) (smem + (b) * 32768 + (kh) * 8192 + wid * 2048 + (q) * 1024)
#define B_SLOT(b, kh, q) (smem + (b) * 32768 + 16384 + (kh) * 8192 + wid * 2048 + (q) * 1024)
#define STAGE(b, kh, kt)                                                   \
    {                                                                      \
        size_t ko = (size_t)(kt) * 64 + (kh) * 32;                         \
        GLOAD_LDS16(Abase + ko, A_SLOT(b, kh, 0));                         \
        GLOAD_LDS16(Abase + 16 * 768 + ko, A_SLOT(b, kh, 1));              \
        GLOAD_LDS16(Bbase + ko, B_SLOT(b, kh, 0));                         \
        GLOAD_LDS16(Bbase + 16 * 768 + ko, B_SLOT(b, kh, 1));              \
    }

    const f32x4 zero4 = {0.f, 0.f, 0.f, 0.f};
    f32x4 acc[4][4];
#pragma unroll
    for (int i = 0; i < 4; i++)
#pragma unroll
        for (int j = 0; j < 4; j++) acc[i][j] = zero4;

    // prologue: tile0 (k0,k1) + tile1 k0 = 12 loads; wait for tile0 k0 only
    STAGE(0, 0, 0);
    STAGE(0, 1, 0);
    STAGE(1, 0, 1);
    asm volatile("s_waitcnt vmcnt(8)" ::: "memory");
    __builtin_amdgcn_s_barrier();

    for (int t = 0; t < 12; t++) {
        const int buf = t & 1;
        const int t1 = (t + 1 < 12) ? t + 1 : t - 11;
        const int t2 = (t + 2 < 12) ? t + 2 : t - 10;
#pragma unroll
        for (int kk = 0; kk < 2; kk++) {
            // ds-read this phase's fragments (2-way-free swizzled)
            const short* Ab = (const short*)(smem + buf * 32768 + kk * 8192);
            const short* Bb = (const short*)(smem + buf * 32768 + 16384 + kk * 8192);
            bf16x8 af[4], bfr[4];
#pragma unroll
            for (int mi = 0; mi < 4; mi++) {
                int row = wm * 64 + mi * 16 + c;
                af[mi] = *(const bf16x8*)&Ab[row * 32 + ((g ^ ((row >> 1) & 3)) << 3)];
            }
#pragma unroll
            for (int ni = 0; ni < 4; ni++) {
                int row = wn * 64 + ni * 16 + c;
                bfr[ni] = *(const bf16x8*)&Bb[row * 32 + ((g ^ ((row >> 1) & 3)) << 3)];
            }
            // rolling prefetch: P1 -> k1(t+1) into buf^1; P2 -> k0(t+2) into buf
            if (kk == 0) STAGE(buf ^ 1, 1, t1)
            else         STAGE(buf, 0, t2)
            __builtin_amdgcn_s_barrier();
            __builtin_amdgcn_s_setprio(1);
#pragma unroll
            for (int mi = 0; mi < 4; mi++)
#pragma unroll
                for (int ni = 0; ni < 4; ni++)
                    acc[mi][ni] = __builtin_amdgcn_mfma_f32_16x16x32_bf16(
                        af[mi], bfr[ni], acc[mi][ni], 0, 0, 0);
            __builtin_amdgcn_s_setprio(0);
            asm volatile("s_waitcnt vmcnt(8)" ::: "memory");
            __builtin_amdgcn_s_barrier();
        }
    }

    // Drain ALL outstanding global_load_lds DMAs before the epilogue and before
    // endpgm, for BOTH EPI paths (r6 race fix: in-flight DMA from a finished
    // block corrupts the next block's LDS in the same CU slot).
    asm volatile("s_waitcnt vmcnt(0)" ::: "memory");
    __builtin_amdgcn_s_barrier();

    if (EPI == 0) {
        // Phase 1: RoPE on (even,odd) col pairs -> swizzled LDS [128][64 words]
        uint32_t* LD = (uint32_t*)smem;   // 32 KB
#pragma unroll
        for (int ni = 0; ni < 4; ni++) {
            int nl = wn * 64 + ni * 16 + c;
            int n = n0 + nl;
            float bv = bias[n];
            int part = (n >= 1536) ? 2 : (n >= 768 ? 1 : 0);
            int d = (n - part * 768) & 63;
#pragma unroll
            for (int mi = 0; mi < 4; mi++) {
#pragma unroll
                for (int r = 0; r < 4; r++) {
                    int ml = wm * 64 + mi * 16 + g * 4 + r;
                    float v = acc[mi][ni][r] + bv;
                    float pv = __shfl_xor(v, 1);   // partner col n^1 (all lanes exec)
                    if (!(c & 1)) {
                        float o0, o1;
                        if (part < 2) {
                            int t = (m0 + ml) & 1023;
                            float2 cs = fc[t * 32 + (d >> 1)];
                            o0 = v * cs.x - pv * cs.y;
                            o1 = v * cs.y + pv * cs.x;
                            if (part == 0) { o0 *= 0.125f; o1 *= 0.125f; }
                        } else { o0 = v; o1 = pv; }
                        LD[ml * 64 + ((nl >> 1) ^ (((ml >> 2) & 3) << 3))] = bfpack(o0, o1);
                    }
                }
            }
        }
        __syncthreads();
        // Phase 2: coalesced 16B scatter stores.
#pragma unroll
        for (int p = 0; p < 8; p++) {
            int ml = p * 16 + (tid >> 4);
            int wc = (tid & 15) * 4;
            int4 dat = *(const int4*)&LD[ml * 64 + (wc ^ (((ml >> 2) & 3) << 3))];
            int n = n0 + wc * 2;
            int part = (n >= 1536) ? 2 : (n >= 768 ? 1 : 0);
            int rem = n - part * 768;
            int h = rem >> 6, d = rem & 63;
            int m = m0 + ml, b = m >> 10, t = m & 1023;
            short* dst = (part == 0 ? Qb : part == 1 ? Kb : Vb)
                         + (((size_t)b * NH + h) * TT + t) * HD + d;
            *(int4*)dst = dat;
        }
    } else {
#pragma unroll
        for (int mi = 0; mi < 4; mi++)
#pragma unroll
            for (int ni = 0; ni < 4; ni++) {
                int n = n0 + wn * 64 + ni * 16 + c;
                float bv = bias[n];
#pragma unroll
                for (int r = 0; r < 4; r++) {
                    int m = m0 + wm * 64 + mi * 16 + g * 4 + r;
                    out[(size_t)m * CC + n] = acc[mi][ni][r] + bv;
                }
            }
    }
#undef A_SLOT
#undef B_SLOT
#undef STAGE
}

// ---------------------------------------------------------------- flash attention
// (unchanged — passed 3x; swapped-operand S^T = mfma(K,Q), lane-local softmax,
// per-wave barrier-free LDS P-tile, V from global VT, LDS O^T epilogue)
__global__ __launch_bounds__(256)
void attn_kernel(const short* __restrict__ Qb, const short* __restrict__ Kb,
                 const short* __restrict__ VT, short* __restrict__ Ob) {
    __shared__ uint32_t Pt[4][32][32];  // 16 KB per-wave P tile, XOR-swizzled
    __shared__ uint32_t ot[128 * 32];   // 16 KB epilogue O^T transpose
    const int tid = threadIdx.x, lane = tid & 63, wid = tid >> 6;
    const int g = lane >> 4, c = lane & 15;
    const int bh = blockIdx.x, qb = 7 - (int)blockIdx.y;
    const int b = bh / NH, h = bh % NH;
    const short* Qp = Qb + (size_t)bh * TT * HD;
    const short* Kp = Kb + (size_t)bh * TT * HD;
    const short* Vp = VT + (size_t)bh * TT * HD;
    const int q0 = qb * 128 + wid * 32;
    const int sw = (c & 7) << 2;

    bf16x8 qf[2][2];
#pragma unroll
    for (int qs = 0; qs < 2; qs++)
#pragma unroll
        for (int kh = 0; kh < 2; kh++)
            qf[qs][kh] = *(const bf16x8*)(Qp + (size_t)(q0 + qs * 16 + c) * HD + kh * 32 + g * 8);

    const f32x4 zero4 = {0.f, 0.f, 0.f, 0.f};
    f32x4 o[2][4];
#pragma unroll
    for (int qs = 0; qs < 2; qs++)
#pragma unroll
        for (int dt = 0; dt < 4; dt++) o[qs][dt] = zero4;
    float mrun[2] = {-1e30f, -1e30f}, lrun[2] = {0.f, 0.f};

    const int t0max = ((q0 + 31) >> 6) << 6;
    for (int t0 = 0; t0 <= t0max; t0 += 64) {
        f32x4 st[2][4];
#pragma unroll
        for (int nt = 0; nt < 4; nt++) {
            const short* kp = Kp + (size_t)(t0 + nt * 16 + c) * HD + g * 8;
            bf16x8 k0 = *(const bf16x8*)kp;
            bf16x8 k1 = *(const bf16x8*)(kp + 32);
#pragma unroll
            for (int qs = 0; qs < 2; qs++) {
                f32x4 z = zero4;
                z = __builtin_amdgcn_mfma_f32_16x16x32_bf16(k0, qf[qs][0], z, 0, 0, 0);
                z = __builtin_amdgcn_mfma_f32_16x16x32_bf16(k1, qf[qs][1], z, 0, 0, 0);
                st[qs][nt] = z;
            }
        }
        bf16x8 vf[2][4];
#pragma unroll
        for (int blk = 0; blk < 2; blk++)
#pragma unroll
            for (int dt = 0; dt < 4; dt++)
                vf[blk][dt] = *(const bf16x8*)(Vp + (size_t)(dt * 16 + c) * TT + t0 + blk * 32 + g * 8);
        if (t0 + 63 > q0) {
#pragma unroll
            for (int qs = 0; qs < 2; qs++) {
                int q = q0 + qs * 16 + c;
#pragma unroll
                for (int nt = 0; nt < 4; nt++)
#pragma unroll
                    for (int r = 0; r < 4; r++)
                        if (t0 + nt * 16 + g * 4 + r > q) st[qs][nt][r] = -1e30f;
            }
        }
#pragma unroll
        for (int qs = 0; qs < 2; qs++) {
            float mx = st[qs][0][0];
#pragma unroll
            for (int nt = 0; nt < 4; nt++)
#pragma unroll
                for (int r = 0; r < 4; r++) mx = fmaxf(mx, st[qs][nt][r]);
            mx = fmaxf(mx, __shfl_xor(mx, 16));
            mx = fmaxf(mx, __shfl_xor(mx, 32));
            float mnew = fmaxf(mrun[qs], mx);
            float al = __expf(mrun[qs] - mnew);
            mrun[qs] = mnew;
            float sm = 0.f;
#pragma unroll
            for (int nt = 0; nt < 4; nt++)
#pragma unroll
                for (int r = 0; r < 4; r++) {
                    float e = __expf(st[qs][nt][r] - mnew);
                    st[qs][nt][r] = e;
                    sm += e;
                }
            sm += __shfl_xor(sm, 16);
            sm += __shfl_xor(sm, 32);
            lrun[qs] = lrun[qs] * al + sm;
#pragma unroll
            for (int dt = 0; dt < 4; dt++) {
                o[qs][dt][0] *= al; o[qs][dt][1] *= al;
                o[qs][dt][2] *= al; o[qs][dt][3] *= al;
            }
            int row = qs * 16 + c;
#pragma unroll
            for (int nt = 0; nt < 4; nt++) {
                uint32_t w0 = bfpack(st[qs][nt][0], st[qs][nt][1]);
                uint32_t w1 = bfpack(st[qs][nt][2], st[qs][nt][3]);
                int wa = nt * 8 + 2 * g;
                Pt[wid][row][wa ^ sw]       = w0;
                Pt[wid][row][(wa + 1) ^ sw] = w1;
            }
        }
#pragma unroll
        for (int qs = 0; qs < 2; qs++) {
            int row = qs * 16 + c;
#pragma unroll
            for (int blk = 0; blk < 2; blk++) {
                bf16x8 pf = *(const bf16x8*)&Pt[wid][row][(blk * 16 + 4 * g) ^ sw];
#pragma unroll
                for (int dt = 0; dt < 4; dt++)
                    o[qs][dt] = __builtin_amdgcn_mfma_f32_16x16x32_bf16(
                        vf[blk][dt], pf, o[qs][dt], 0, 0, 0);
            }
        }
    }

#pragma unroll
    for (int qs = 0; qs < 2; qs++) {
        float inv = 1.0f / lrun[qs];
        int ql = wid * 32 + qs * 16 + c;
#pragma unroll
        for (int dt = 0; dt < 4; dt++) {
            uint32_t w0 = bfpack(o[qs][dt][0] * inv, o[qs][dt][1] * inv);
            uint32_t w1 = bfpack(o[qs][dt][2] * inv, o[qs][dt][3] * inv);
            int jc0 = dt * 8 + 2 * g;
            int jc1 = jc0 + 1;
            ot[ql * 32 + ((((jc0 >> 2) ^ (c & 7)) << 2) | (jc0 & 3))] = w0;
            ot[ql * 32 + ((((jc1 >> 2) ^ (c & 7)) << 2) | (jc1 & 3))] = w1;
        }
    }
    __syncthreads();
#pragma unroll
    for (int p = 0; p < 4; p++) {
        int q = (tid >> 3) + 32 * p;
        int jb = tid & 7;
        const uint32_t* src = &ot[q * 32 + ((jb ^ (q & 7)) << 2)];
        int4 w = *(const int4*)src;
        *(int4*)(Ob + ((size_t)b * TT + qb * 128 + q) * CC + h * HD + jb * 8) = w;
    }
}

// ---------------------------------------------------------------- launch
extern "C" void kernel_launch(void* const* d_in, const int* in_sizes, int n_in,
                              void* d_out, int out_size, void* d_ws, size_t ws_size,
                              hipStream_t stream) {
    const float* x     = (const float*)d_in[0];
    const float* Wqkv  = (const float*)d_in[1];
    const float* bqkv  = (const float*)d_in[2];
    const float* Wproj = (const float*)d_in[3];
    const float* bproj = (const float*)d_in[4];
    // d_in[5] = mask: causal by construction, unused

    char* ws = (char*)d_ws;
    // ws layout: WqkvT 3538944 | WprojT 1179648 | fc 262144 | Qb | Kb | V/Ob | VbT
    // xb (bf16 x) ALIASES VbT: xb consumed by gemm1, VbT written later by vtrans.
    short*  WqkvT  = (short*)(ws);
    short*  WprojT = (short*)(ws + 3538944);
    float2* fc     = (float2*)(ws + 3538944 + 1179648);
    short*  Qb     = (short*)(ws + 4980736);
    short*  Kb     = (short*)(ws + 4980736 + 1 * 12582912);
    short*  VOb    = (short*)(ws + 4980736 + 2 * 12582912);  // V, then O after vtrans
    short*  VbT    = (short*)(ws + 4980736 + 3 * 12582912);
    short*  xb     = VbT;
    float*  out    = (float*)d_out;

    hipLaunchKernelGGL(fc_kernel, dim3(128), dim3(256), 0, stream, fc);
    hipLaunchKernelGGL(transpose_cast_kernel, dim3(72, 24), dim3(32, 8), 0, stream,
                       Wqkv, WqkvT, 768, 2304);
    hipLaunchKernelGGL(transpose_cast_kernel, dim3(24, 24), dim3(32, 8), 0, stream,
                       Wproj, WprojT, 768, 768);
    hipLaunchKernelGGL(cast_kernel, dim3(3072), dim3(256), 0, stream, x, xb);
    hipLaunchKernelGGL((gemm_kernel<0>), dim3(18, 64), dim3(256), 0, stream,
                       xb, WqkvT, bqkv, Qb, Kb, VOb, fc, (float*)nullptr);
    hipLaunchKernelGGL(vtrans_kernel, dim3(16, 96), dim3(256), 0, stream, VOb, VbT);
    hipLaunchKernelGGL(attn_kernel, dim3(96, 8), dim3(256), 0, stream, Qb, Kb, VbT, VOb);
    hipLaunchKernelGGL((gemm_kernel<1>), dim3(6, 64), dim3(256), 0, stream,
                       VOb, WprojT, bproj,
                       (short*)nullptr, (short*)nullptr, (short*)nullptr,
                       (const float2*)nullptr, out);
}